// Round 9
// baseline (743.819 us; speedup 1.0000x reference)
//
#include <hip/hip_runtime.h>

#define N_USERS 100000
#define N_ITEMS 50000
#define N_TOPICS 1000
#define N_NODES (N_USERS + N_ITEMS + N_TOPICS)   // 151000
#define DIM 64
#define NNZ 4000000
#define BATCH 16384

#define BROWS 128                                 // rows per bucket
#define NB ((N_NODES + BROWS - 1) / BROWS)        // 1180 buckets
#define NPART 512                                 // partition blocks
#define CHUNK ((NNZ + NPART - 1) / NPART)         // 7813 edges per block
#define SEGCAP 4608                               // LDS seg capacity (36 KB)

// ---------------------------------------------------------------------------
// Build X0 = concat(user_w, item_w, topic_w). One float4 (4 dims) per thread.
// ---------------------------------------------------------------------------
__global__ void concat_init(const float4* __restrict__ uw,
                            const float4* __restrict__ iw,
                            const float4* __restrict__ tw,
                            float4* __restrict__ x0) {
    int tid = blockIdx.x * blockDim.x + threadIdx.x;   // node*16 + q
    const int total = N_NODES * (DIM / 4);
    if (tid >= total) return;
    int node = tid >> 4;
    int q = tid & 15;
    float4 v;
    if (node < N_USERS)                v = uw[node * 16 + q];
    else if (node < N_USERS + N_ITEMS) v = iw[(node - N_USERS) * 16 + q];
    else                               v = tw[(node - N_USERS - N_ITEMS) * 16 + q];
    x0[tid] = v;
}

// ---------------------------------------------------------------------------
// Partition phase 1: per-block bucket histogram of its contiguous chunk.
// ---------------------------------------------------------------------------
__global__ void __launch_bounds__(256)
part_count(const int* __restrict__ row, int* __restrict__ hcnt) {
    __shared__ int h[NB];
    const int g = blockIdx.x;
    const int t = threadIdx.x;
    for (int i = t; i < NB; i += 256) h[i] = 0;
    __syncthreads();
    int e0 = g * CHUNK;
    int e1 = e0 + CHUNK; if (e1 > NNZ) e1 = NNZ;
    for (int e = e0 + t; e < e1; e += 256) {
        int r = __builtin_nontemporal_load(&row[e]);
        atomicAdd(&h[r >> 7], 1);
    }
    __syncthreads();
    int* dst = hcnt + (size_t)g * NB;
    for (int i = t; i < NB; i += 256) dst[i] = h[i];
}

// ---------------------------------------------------------------------------
// Partition phase 2a: per-bucket exclusive scan across the NPART blocks.
// ---------------------------------------------------------------------------
__global__ void part_scanA(int* __restrict__ hcnt, int* __restrict__ bcnt) {
    int b = blockIdx.x * 4 + (threadIdx.x >> 6);
    int lane = threadIdx.x & 63;
    if (b >= NB) return;
    int carry = 0;
    for (int base = 0; base < NPART; base += 64) {
        int g = base + lane;
        int v = hcnt[(size_t)g * NB + b];
        int x = v;
        #pragma unroll
        for (int off = 1; off < 64; off <<= 1) {
            int y = __shfl_up(x, off, 64);
            if (lane >= off) x += y;
        }
        int tot = __shfl(x, 63, 64);
        hcnt[(size_t)g * NB + b] = carry + x - v;
        carry += tot;
    }
    if (lane == 0) bcnt[b] = carry;
}

// ---------------------------------------------------------------------------
// Partition phase 2b: exclusive scan over NB bucket totals (single block).
// ---------------------------------------------------------------------------
__global__ void part_scanB(const int* __restrict__ bcnt,
                           int* __restrict__ bptr,
                           int* __restrict__ rowptr) {
    __shared__ int wsum[16];
    __shared__ int carry_s;
    const int t = threadIdx.x;
    const int lane = t & 63;
    const int wid = t >> 6;
    if (t == 0) carry_s = 0;
    __syncthreads();
    for (int base = 0; base < NB; base += 1024) {
        int i = base + t;
        int v = (i < NB) ? bcnt[i] : 0;
        int x = v;
        #pragma unroll
        for (int off = 1; off < 64; off <<= 1) {
            int y = __shfl_up(x, off, 64);
            if (lane >= off) x += y;
        }
        if (lane == 63) wsum[wid] = x;
        __syncthreads();
        int wbase = 0;
        for (int w = 0; w < wid; ++w) wbase += wsum[w];
        int excl = carry_s + wbase + (x - v);
        if (i < NB) bptr[i] = excl;
        __syncthreads();
        if (t == 1023) carry_s = excl + v;
        __syncthreads();
    }
    if (t == 0) { bptr[NB] = NNZ; rowptr[N_NODES] = NNZ; }
}

// ---------------------------------------------------------------------------
// Partition phase 3: atomic-free scatter via per-(block,bucket) offsets.
// ---------------------------------------------------------------------------
__global__ void __launch_bounds__(256)
part_scatter(const int* __restrict__ row,
             const int* __restrict__ col,
             const float* __restrict__ vals,
             const int* __restrict__ hcnt,
             const int* __restrict__ bptr,
             int2* __restrict__ cvtmp) {
    __shared__ int cur[NB];
    const int g = blockIdx.x;
    const int t = threadIdx.x;
    const int* hoff = hcnt + (size_t)g * NB;
    for (int i = t; i < NB; i += 256) cur[i] = bptr[i] + hoff[i];
    __syncthreads();
    int e0 = g * CHUNK;
    int e1 = e0 + CHUNK; if (e1 > NNZ) e1 = NNZ;
    for (int e = e0 + t; e < e1; e += 256) {
        int r = __builtin_nontemporal_load(&row[e]);
        int c = __builtin_nontemporal_load(&col[e]);
        float v = __builtin_nontemporal_load(&vals[e]);
        int p = atomicAdd(&cur[r >> 7], 1);
        cvtmp[p] = make_int2(((r & (BROWS - 1)) << 18) | c, __float_as_int(v));
    }
}

// ---------------------------------------------------------------------------
// Bucket-local counting sort -> row-sorted CSR (cv) + rowptr.
// Segment staged in LDS once (<=36 KB); nt stores for cv (stream-out).
// ---------------------------------------------------------------------------
__global__ void __launch_bounds__(256)
bucket_sort(const int* __restrict__ bptr,
            const long long* __restrict__ cvtmp,
            long long* __restrict__ cv,
            int* __restrict__ rowptr) {
    __shared__ int2 seg[SEGCAP];     // 36 KB
    __shared__ int cnt[BROWS];
    __shared__ int cur[BROWS];
    const int t = threadIdx.x;
    const int b = blockIdx.x;
    const int beg = bptr[b];
    const int end = bptr[b + 1];
    const int n = end - beg;

    for (int i = t; i < BROWS; i += 256) cnt[i] = 0;
    const bool lds_path = (n <= SEGCAP);

    if (lds_path) {
        for (int j = t; j < n; j += 256) {
            long long e = cvtmp[beg + j];
            seg[j] = make_int2((int)e, (int)(e >> 32));
        }
    }
    __syncthreads();

    // pass 1: per-row counts
    if (lds_path) {
        for (int j = t; j < n; j += 256)
            atomicAdd(&cnt[(seg[j].x >> 18) & (BROWS - 1)], 1);
    } else {
        for (int j = beg + t; j < end; j += 256) {
            long long e = cvtmp[j];
            atomicAdd(&cnt[((int)e >> 18) & (BROWS - 1)], 1);
        }
    }
    __syncthreads();

    // exclusive scan of 128 counts on wave 0; also emit rowptr
    if (t < 64) {
        int lane = t;
        int v0 = cnt[lane];
        int v1 = cnt[64 + lane];
        int x0 = v0;
        #pragma unroll
        for (int off = 1; off < 64; off <<= 1) {
            int y = __shfl_up(x0, off, 64);
            if (lane >= off) x0 += y;
        }
        int tot0 = __shfl(x0, 63, 64);
        int x1 = v1;
        #pragma unroll
        for (int off = 1; off < 64; off <<= 1) {
            int y = __shfl_up(x1, off, 64);
            if (lane >= off) x1 += y;
        }
        x1 += tot0;
        int e0 = x0 - v0;
        int e1 = x1 - v1;
        cur[lane] = e0;
        cur[64 + lane] = e1;
        int rowbase = b * BROWS;
        if (rowbase + lane < N_NODES)      rowptr[rowbase + lane] = beg + e0;
        if (rowbase + 64 + lane < N_NODES) rowptr[rowbase + 64 + lane] = beg + e1;
    }
    __syncthreads();

    // pass 2: scatter into row-sorted order, strip row bits, nt store
    if (lds_path) {
        for (int j = t; j < n; j += 256) {
            int2 e = seg[j];
            int p = atomicAdd(&cur[(e.x >> 18) & (BROWS - 1)], 1);
            long long outv = ((long long)(unsigned)e.y << 32) |
                             (unsigned)(e.x & 0x3FFFF);
            __builtin_nontemporal_store(outv, &cv[beg + p]);
        }
    } else {
        for (int j = beg + t; j < end; j += 256) {
            long long e = cvtmp[j];
            int lo = (int)e;
            int hi = (int)(e >> 32);
            int p = atomicAdd(&cur[(lo >> 18) & (BROWS - 1)], 1);
            long long outv = ((long long)(unsigned)hi << 32) |
                             (unsigned)(lo & 0x3FFFF);
            __builtin_nontemporal_store(outv, &cv[beg + p]);
        }
    }
}

// ---------------------------------------------------------------------------
// SpMM over CSR: one 64-lane wave per row, lane = dim. Unroll-16, 4 acc
// chains -> ~16 outstanding gathers/wave. cv read nontemporal (stream-once,
// keeps x working set in L2).
// ---------------------------------------------------------------------------
__global__ void spmm_csr(const int* __restrict__ rowptr,
                         const long long* __restrict__ cv,
                         const float* __restrict__ x,
                         float* __restrict__ y) {
    int r = blockIdx.x * 4 + (threadIdx.x >> 6);
    int lane = threadIdx.x & 63;
    if (r >= N_NODES) return;
    int beg = rowptr[r];
    int end = rowptr[r + 1];
    float a0 = 0.0f, a1 = 0.0f, a2 = 0.0f, a3 = 0.0f;
    int j = beg;
    for (; j + 15 < end; j += 16) {
        float xs[16], vs[16];
        #pragma unroll
        for (int k = 0; k < 16; ++k) {
            long long e = __builtin_nontemporal_load(&cv[j + k]);
            vs[k] = __int_as_float((int)(e >> 32));
            xs[k] = x[(size_t)(int)e * 64 + lane];
        }
        #pragma unroll
        for (int k = 0; k < 16; k += 4) {
            a0 = fmaf(vs[k + 0], xs[k + 0], a0);
            a1 = fmaf(vs[k + 1], xs[k + 1], a1);
            a2 = fmaf(vs[k + 2], xs[k + 2], a2);
            a3 = fmaf(vs[k + 3], xs[k + 3], a3);
        }
    }
    for (; j + 3 < end; j += 4) {
        float xs[4], vs[4];
        #pragma unroll
        for (int k = 0; k < 4; ++k) {
            long long e = __builtin_nontemporal_load(&cv[j + k]);
            vs[k] = __int_as_float((int)(e >> 32));
            xs[k] = x[(size_t)(int)e * 64 + lane];
        }
        a0 = fmaf(vs[0], xs[0], a0);
        a1 = fmaf(vs[1], xs[1], a1);
        a2 = fmaf(vs[2], xs[2], a2);
        a3 = fmaf(vs[3], xs[3], a3);
    }
    for (; j < end; ++j) {
        long long e = __builtin_nontemporal_load(&cv[j]);
        a0 = fmaf(__int_as_float((int)(e >> 32)),
                  x[(size_t)(int)e * 64 + lane], a0);
    }
    y[(size_t)r * 64 + lane] = (a0 + a1) + (a2 + a3);
}

// ---------------------------------------------------------------------------
// Layer-3 SpMM restricted to batch rows (~870K edges), same ILP structure,
// accumulating straight into ACCB.
// ---------------------------------------------------------------------------
__global__ void spmm_batch(const int* __restrict__ rowptr,
                           const long long* __restrict__ cv,
                           const float* __restrict__ x,
                           const int* __restrict__ users,
                           const int* __restrict__ items,
                           float* __restrict__ accb) {
    int b = blockIdx.x * 4 + (threadIdx.x >> 6);
    int lane = threadIdx.x & 63;
    if (b >= 2 * BATCH) return;
    int r = (b < BATCH) ? users[b] : (N_USERS + items[b - BATCH]);
    int beg = rowptr[r];
    int end = rowptr[r + 1];
    float a0 = 0.0f, a1 = 0.0f, a2 = 0.0f, a3 = 0.0f;
    int j = beg;
    for (; j + 15 < end; j += 16) {
        float xs[16], vs[16];
        #pragma unroll
        for (int k = 0; k < 16; ++k) {
            long long e = __builtin_nontemporal_load(&cv[j + k]);
            vs[k] = __int_as_float((int)(e >> 32));
            xs[k] = x[(size_t)(int)e * 64 + lane];
        }
        #pragma unroll
        for (int k = 0; k < 16; k += 4) {
            a0 = fmaf(vs[k + 0], xs[k + 0], a0);
            a1 = fmaf(vs[k + 1], xs[k + 1], a1);
            a2 = fmaf(vs[k + 2], xs[k + 2], a2);
            a3 = fmaf(vs[k + 3], xs[k + 3], a3);
        }
    }
    for (; j + 3 < end; j += 4) {
        float xs[4], vs[4];
        #pragma unroll
        for (int k = 0; k < 4; ++k) {
            long long e = __builtin_nontemporal_load(&cv[j + k]);
            vs[k] = __int_as_float((int)(e >> 32));
            xs[k] = x[(size_t)(int)e * 64 + lane];
        }
        a0 = fmaf(vs[0], xs[0], a0);
        a1 = fmaf(vs[1], xs[1], a1);
        a2 = fmaf(vs[2], xs[2], a2);
        a3 = fmaf(vs[3], xs[3], a3);
    }
    for (; j < end; ++j) {
        long long e = __builtin_nontemporal_load(&cv[j]);
        a0 = fmaf(__int_as_float((int)(e >> 32)),
                  x[(size_t)(int)e * 64 + lane], a0);
    }
    size_t o = (size_t)b * 64 + lane;
    accb[o] += (a0 + a1) + (a2 + a3);
}

// ---------------------------------------------------------------------------
// Batch accumulator init: accb[b] = user_w[users[b]], accb[B+b] = item_w[items[b]]
// ---------------------------------------------------------------------------
__global__ void batch_init(const float4* __restrict__ uw,
                           const float4* __restrict__ iw,
                           const int* __restrict__ users,
                           const int* __restrict__ items,
                           float4* __restrict__ accb) {
    int tid = blockIdx.x * blockDim.x + threadIdx.x;   // row*16 + q
    const int total = 2 * BATCH * (DIM / 4);
    if (tid >= total) return;
    int r = tid >> 4;
    int q = tid & 15;
    float4 v;
    if (r < BATCH) v = uw[(size_t)users[r] * 16 + q];
    else           v = iw[(size_t)items[r - BATCH] * 16 + q];
    accb[tid] = v;
}

// ---------------------------------------------------------------------------
// Batch accumulator add from full node table (layers 1,2).
// ---------------------------------------------------------------------------
__global__ void batch_add(const float4* __restrict__ emb,
                          const int* __restrict__ users,
                          const int* __restrict__ items,
                          float4* __restrict__ accb) {
    int tid = blockIdx.x * blockDim.x + threadIdx.x;
    const int total = 2 * BATCH * (DIM / 4);
    if (tid >= total) return;
    int r = tid >> 4;
    int q = tid & 15;
    int node = (r < BATCH) ? users[r] : (N_USERS + items[r - BATCH]);
    float4 v = emb[(size_t)node * 16 + q];
    float4 a = accb[tid];
    a.x += v.x; a.y += v.y; a.z += v.z; a.w += v.w;
    accb[tid] = a;
}

// ---------------------------------------------------------------------------
// Final dot: out[b] = (accb[b] . accb[BATCH+b]) / 16
// ---------------------------------------------------------------------------
__global__ void final_dot(const float* __restrict__ accb,
                          float* __restrict__ out) {
    int b = blockIdx.x * 4 + (threadIdx.x >> 6);
    int lane = threadIdx.x & 63;
    if (b >= BATCH) return;
    float pu = accb[(size_t)b * 64 + lane];
    float pi = accb[(size_t)(BATCH + b) * 64 + lane];
    float p = pu * pi;
    #pragma unroll
    for (int off = 32; off > 0; off >>= 1)
        p += __shfl_down(p, off, 64);
    if (lane == 0) out[b] = p * (1.0f / 16.0f);
}

extern "C" void kernel_launch(void* const* d_in, const int* in_sizes, int n_in,
                              void* d_out, int out_size, void* d_ws, size_t ws_size,
                              hipStream_t stream) {
    const float* uw   = (const float*)d_in[0];
    const float* iw   = (const float*)d_in[1];
    const float* tw   = (const float*)d_in[2];
    const float* vals = (const float*)d_in[3];
    const int*   row  = (const int*)d_in[4];
    const int*   col  = (const int*)d_in[5];
    const int*   users= (const int*)d_in[6];
    const int*   items= (const int*)d_in[7];
    float* out = (float*)d_out;

    // ---- workspace layout ----
    char* ws = (char*)d_ws;
    const size_t NODE_F = (size_t)N_NODES * DIM;       // 9,664,000 floats
    float* A      = (float*)ws;  ws += NODE_F * 4;     // also reused as cvtmp
    float* B      = (float*)ws;  ws += NODE_F * 4;
    float* ACCB   = (float*)ws;  ws += (size_t)2 * BATCH * DIM * 4;
    int*   bcnt   = (int*)ws;    ws += (size_t)NB * 4;
    int*   bptr   = (int*)ws;    ws += (size_t)(NB + 1) * 4;
    int*   rowptr = (int*)ws;    ws += (size_t)(N_NODES + 1) * 4;
    int*   hcnt   = (int*)ws;    ws += (size_t)NPART * NB * 4;   // 2.42 MB
    long long* cv = (long long*)ws; ws += (size_t)NNZ * 8;
    int2*  cvtmp  = (int2*)A;    // 32 MB staging inside A's 38.7 MB; consumed
                                 // before concat_init writes A (stream order)

    const int node_v4  = N_NODES * (DIM / 4);
    const int batch_v4 = 2 * BATCH * (DIM / 4);

    // ---- atomic-free bucketed partition + bucket-local sort -> CSR ----
    part_count<<<NPART, 256, 0, stream>>>(row, hcnt);
    part_scanA<<<(NB + 3) / 4, 256, 0, stream>>>(hcnt, bcnt);
    part_scanB<<<1, 1024, 0, stream>>>(bcnt, bptr, rowptr);
    part_scatter<<<NPART, 256, 0, stream>>>(row, col, vals, hcnt, bptr, cvtmp);
    bucket_sort<<<NB, 256, 0, stream>>>(bptr, (const long long*)cvtmp, cv, rowptr);

    // ---- layer-0 embedding + batch accumulator init ----
    concat_init<<<(node_v4 + 255) / 256, 256, 0, stream>>>(
        (const float4*)uw, (const float4*)iw, (const float4*)tw, (float4*)A);
    batch_init<<<(batch_v4 + 255) / 256, 256, 0, stream>>>(
        (const float4*)uw, (const float4*)iw, users, items, (float4*)ACCB);

    // ---- layers 1,2: full SpMM; layer 3: batch rows only ----
    const int spmm_blocks = (N_NODES + 3) / 4;   // 4 row-waves per 256-block
    spmm_csr<<<spmm_blocks, 256, 0, stream>>>(rowptr, cv, A, B);
    batch_add<<<(batch_v4 + 255) / 256, 256, 0, stream>>>(
        (const float4*)B, users, items, (float4*)ACCB);
    spmm_csr<<<spmm_blocks, 256, 0, stream>>>(rowptr, cv, B, A);
    batch_add<<<(batch_v4 + 255) / 256, 256, 0, stream>>>(
        (const float4*)A, users, items, (float4*)ACCB);
    spmm_batch<<<(2 * BATCH + 3) / 4, 256, 0, stream>>>(
        rowptr, cv, A, users, items, ACCB);

    final_dot<<<(BATCH + 3) / 4, 256, 0, stream>>>(ACCB, out);
}

// Round 10
// 625.399 us; speedup vs baseline: 1.1894x; 1.1894x over previous
//
#include <hip/hip_runtime.h>

#define N_USERS 100000
#define N_ITEMS 50000
#define N_TOPICS 1000
#define N_NODES (N_USERS + N_ITEMS + N_TOPICS)   // 151000
#define DIM 64
#define NNZ 4000000
#define BATCH 16384

#define BROWS 128                                 // rows per bucket
#define NB ((N_NODES + BROWS - 1) / BROWS)        // 1180 buckets
#define NPART 512                                 // partition blocks
#define CHUNK ((NNZ + NPART - 1) / NPART)         // 7813 edges per block
#define SEGCAP 4608                               // LDS seg capacity (36 KB)

// ---------------------------------------------------------------------------
// Build X0 = concat(user_w, item_w, topic_w). One float4 (4 dims) per thread.
// ---------------------------------------------------------------------------
__global__ void concat_init(const float4* __restrict__ uw,
                            const float4* __restrict__ iw,
                            const float4* __restrict__ tw,
                            float4* __restrict__ x0) {
    int tid = blockIdx.x * blockDim.x + threadIdx.x;   // node*16 + q
    const int total = N_NODES * (DIM / 4);
    if (tid >= total) return;
    int node = tid >> 4;
    int q = tid & 15;
    float4 v;
    if (node < N_USERS)                v = uw[node * 16 + q];
    else if (node < N_USERS + N_ITEMS) v = iw[(node - N_USERS) * 16 + q];
    else                               v = tw[(node - N_USERS - N_ITEMS) * 16 + q];
    x0[tid] = v;
}

// ---------------------------------------------------------------------------
// Partition phase 1: per-block bucket histogram of its contiguous chunk.
// ---------------------------------------------------------------------------
__global__ void __launch_bounds__(256)
part_count(const int* __restrict__ row, int* __restrict__ hcnt) {
    __shared__ int h[NB];
    const int g = blockIdx.x;
    const int t = threadIdx.x;
    for (int i = t; i < NB; i += 256) h[i] = 0;
    __syncthreads();
    int e0 = g * CHUNK;
    int e1 = e0 + CHUNK; if (e1 > NNZ) e1 = NNZ;
    for (int e = e0 + t; e < e1; e += 256) {
        int r = __builtin_nontemporal_load(&row[e]);
        atomicAdd(&h[r >> 7], 1);
    }
    __syncthreads();
    int* dst = hcnt + (size_t)g * NB;
    for (int i = t; i < NB; i += 256) dst[i] = h[i];
}

// ---------------------------------------------------------------------------
// Partition phase 2a: per-bucket exclusive scan across the NPART blocks.
// ---------------------------------------------------------------------------
__global__ void part_scanA(int* __restrict__ hcnt, int* __restrict__ bcnt) {
    int b = blockIdx.x * 4 + (threadIdx.x >> 6);
    int lane = threadIdx.x & 63;
    if (b >= NB) return;
    int carry = 0;
    for (int base = 0; base < NPART; base += 64) {
        int g = base + lane;
        int v = hcnt[(size_t)g * NB + b];
        int x = v;
        #pragma unroll
        for (int off = 1; off < 64; off <<= 1) {
            int y = __shfl_up(x, off, 64);
            if (lane >= off) x += y;
        }
        int tot = __shfl(x, 63, 64);
        hcnt[(size_t)g * NB + b] = carry + x - v;
        carry += tot;
    }
    if (lane == 0) bcnt[b] = carry;
}

// ---------------------------------------------------------------------------
// Partition phase 2b: exclusive scan over NB bucket totals (single block).
// ---------------------------------------------------------------------------
__global__ void part_scanB(const int* __restrict__ bcnt,
                           int* __restrict__ bptr,
                           int* __restrict__ rowptr) {
    __shared__ int wsum[16];
    __shared__ int carry_s;
    const int t = threadIdx.x;
    const int lane = t & 63;
    const int wid = t >> 6;
    if (t == 0) carry_s = 0;
    __syncthreads();
    for (int base = 0; base < NB; base += 1024) {
        int i = base + t;
        int v = (i < NB) ? bcnt[i] : 0;
        int x = v;
        #pragma unroll
        for (int off = 1; off < 64; off <<= 1) {
            int y = __shfl_up(x, off, 64);
            if (lane >= off) x += y;
        }
        if (lane == 63) wsum[wid] = x;
        __syncthreads();
        int wbase = 0;
        for (int w = 0; w < wid; ++w) wbase += wsum[w];
        int excl = carry_s + wbase + (x - v);
        if (i < NB) bptr[i] = excl;
        __syncthreads();
        if (t == 1023) carry_s = excl + v;
        __syncthreads();
    }
    if (t == 0) { bptr[NB] = NNZ; rowptr[N_NODES] = NNZ; }
}

// ---------------------------------------------------------------------------
// Partition phase 3: atomic-free scatter via per-(block,bucket) offsets.
// ---------------------------------------------------------------------------
__global__ void __launch_bounds__(256)
part_scatter(const int* __restrict__ row,
             const int* __restrict__ col,
             const float* __restrict__ vals,
             const int* __restrict__ hcnt,
             const int* __restrict__ bptr,
             int2* __restrict__ cvtmp) {
    __shared__ int cur[NB];
    const int g = blockIdx.x;
    const int t = threadIdx.x;
    const int* hoff = hcnt + (size_t)g * NB;
    for (int i = t; i < NB; i += 256) cur[i] = bptr[i] + hoff[i];
    __syncthreads();
    int e0 = g * CHUNK;
    int e1 = e0 + CHUNK; if (e1 > NNZ) e1 = NNZ;
    for (int e = e0 + t; e < e1; e += 256) {
        int r = __builtin_nontemporal_load(&row[e]);
        int c = __builtin_nontemporal_load(&col[e]);
        float v = __builtin_nontemporal_load(&vals[e]);
        int p = atomicAdd(&cur[r >> 7], 1);
        cvtmp[p] = make_int2(((r & (BROWS - 1)) << 18) | c, __float_as_int(v));
    }
}

// ---------------------------------------------------------------------------
// Bucket-local counting sort -> row-sorted CSR (cv) + rowptr.
// Segment staged in LDS once (<=36 KB). NORMAL stores for cv: block b runs
// on XCD b%8 (round-robin heuristic) and its 27 KB segment stays resident
// in that XCD's L2 for the swizzle-matched first spmm_csr dispatch.
// ---------------------------------------------------------------------------
__global__ void __launch_bounds__(256)
bucket_sort(const int* __restrict__ bptr,
            const long long* __restrict__ cvtmp,
            int2* __restrict__ cv,
            int* __restrict__ rowptr) {
    __shared__ int2 seg[SEGCAP];     // 36 KB
    __shared__ int cnt[BROWS];
    __shared__ int cur[BROWS];
    const int t = threadIdx.x;
    const int b = blockIdx.x;
    const int beg = bptr[b];
    const int end = bptr[b + 1];
    const int n = end - beg;

    for (int i = t; i < BROWS; i += 256) cnt[i] = 0;
    const bool lds_path = (n <= SEGCAP);

    if (lds_path) {
        for (int j = t; j < n; j += 256) {
            long long e = cvtmp[beg + j];
            seg[j] = make_int2((int)e, (int)(e >> 32));
        }
    }
    __syncthreads();

    // pass 1: per-row counts
    if (lds_path) {
        for (int j = t; j < n; j += 256)
            atomicAdd(&cnt[(seg[j].x >> 18) & (BROWS - 1)], 1);
    } else {
        for (int j = beg + t; j < end; j += 256) {
            long long e = cvtmp[j];
            atomicAdd(&cnt[((int)e >> 18) & (BROWS - 1)], 1);
        }
    }
    __syncthreads();

    // exclusive scan of 128 counts on wave 0; also emit rowptr
    if (t < 64) {
        int lane = t;
        int v0 = cnt[lane];
        int v1 = cnt[64 + lane];
        int x0 = v0;
        #pragma unroll
        for (int off = 1; off < 64; off <<= 1) {
            int y = __shfl_up(x0, off, 64);
            if (lane >= off) x0 += y;
        }
        int tot0 = __shfl(x0, 63, 64);
        int x1 = v1;
        #pragma unroll
        for (int off = 1; off < 64; off <<= 1) {
            int y = __shfl_up(x1, off, 64);
            if (lane >= off) x1 += y;
        }
        x1 += tot0;
        int e0 = x0 - v0;
        int e1 = x1 - v1;
        cur[lane] = e0;
        cur[64 + lane] = e1;
        int rowbase = b * BROWS;
        if (rowbase + lane < N_NODES)      rowptr[rowbase + lane] = beg + e0;
        if (rowbase + 64 + lane < N_NODES) rowptr[rowbase + 64 + lane] = beg + e1;
    }
    __syncthreads();

    // pass 2: scatter into row-sorted order, strip row bits
    if (lds_path) {
        for (int j = t; j < n; j += 256) {
            int2 e = seg[j];
            int p = atomicAdd(&cur[(e.x >> 18) & (BROWS - 1)], 1);
            cv[beg + p] = make_int2(e.x & 0x3FFFF, e.y);
        }
    } else {
        for (int j = beg + t; j < end; j += 256) {
            long long e = cvtmp[j];
            int lo = (int)e;
            int hi = (int)(e >> 32);
            int p = atomicAdd(&cur[(lo >> 18) & (BROWS - 1)], 1);
            cv[beg + p] = make_int2(lo & 0x3FFFF, hi);
        }
    }
}

// ---------------------------------------------------------------------------
// SpMM over CSR: one 64-lane wave per row, lane = dim, register acc (R8
// inner loop, known-good). Block->row mapping swizzled so blocks on XCD k
// (blockIdx%8) read buckets with b%8==k, matching bucket_sort's cv writes:
// bucket = (blk>>8)*8 + (blk&7); sub = (blk&255)>>3 -> 4 rows per block.
// ---------------------------------------------------------------------------
__global__ void spmm_csr(const int* __restrict__ rowptr,
                         const int2* __restrict__ cv,
                         const float* __restrict__ x,
                         float* __restrict__ y) {
    int blk = blockIdx.x;
    int bucket = (blk >> 8) * 8 + (blk & 7);
    int sub = (blk & 255) >> 3;
    int r = bucket * BROWS + sub * 4 + (threadIdx.x >> 6);
    int lane = threadIdx.x & 63;
    if (r >= N_NODES) return;
    int beg = rowptr[r];
    int end = rowptr[r + 1];
    float acc0 = 0.0f, acc1 = 0.0f;
    int j = beg;
    for (; j + 7 < end; j += 8) {
        #pragma unroll
        for (int k = 0; k < 8; k += 2) {
            int2 ea = cv[j + k];
            int2 eb = cv[j + k + 1];
            float xa = x[(size_t)ea.x * 64 + lane];
            float xb = x[(size_t)eb.x * 64 + lane];
            acc0 = fmaf(__int_as_float(ea.y), xa, acc0);
            acc1 = fmaf(__int_as_float(eb.y), xb, acc1);
        }
    }
    for (; j < end; ++j) {
        int2 e = cv[j];
        acc0 = fmaf(__int_as_float(e.y), x[(size_t)e.x * 64 + lane], acc0);
    }
    y[(size_t)r * 64 + lane] = acc0 + acc1;
}

// ---------------------------------------------------------------------------
// Layer-3 SpMM restricted to batch rows (~870K edges), R8 form.
// ---------------------------------------------------------------------------
__global__ void spmm_batch(const int* __restrict__ rowptr,
                           const int2* __restrict__ cv,
                           const float* __restrict__ x,
                           const int* __restrict__ users,
                           const int* __restrict__ items,
                           float* __restrict__ accb) {
    int b = blockIdx.x * 4 + (threadIdx.x >> 6);
    int lane = threadIdx.x & 63;
    if (b >= 2 * BATCH) return;
    int r = (b < BATCH) ? users[b] : (N_USERS + items[b - BATCH]);
    int beg = rowptr[r];
    int end = rowptr[r + 1];
    float acc0 = 0.0f, acc1 = 0.0f;
    int j = beg;
    for (; j + 7 < end; j += 8) {
        #pragma unroll
        for (int k = 0; k < 8; k += 2) {
            int2 ea = cv[j + k];
            int2 eb = cv[j + k + 1];
            float xa = x[(size_t)ea.x * 64 + lane];
            float xb = x[(size_t)eb.x * 64 + lane];
            acc0 = fmaf(__int_as_float(ea.y), xa, acc0);
            acc1 = fmaf(__int_as_float(eb.y), xb, acc1);
        }
    }
    for (; j < end; ++j) {
        int2 e = cv[j];
        acc0 = fmaf(__int_as_float(e.y), x[(size_t)e.x * 64 + lane], acc0);
    }
    size_t o = (size_t)b * 64 + lane;
    accb[o] += acc0 + acc1;
}

// ---------------------------------------------------------------------------
// Batch accumulator init: accb[b] = user_w[users[b]], accb[B+b] = item_w[items[b]]
// ---------------------------------------------------------------------------
__global__ void batch_init(const float4* __restrict__ uw,
                           const float4* __restrict__ iw,
                           const int* __restrict__ users,
                           const int* __restrict__ items,
                           float4* __restrict__ accb) {
    int tid = blockIdx.x * blockDim.x + threadIdx.x;   // row*16 + q
    const int total = 2 * BATCH * (DIM / 4);
    if (tid >= total) return;
    int r = tid >> 4;
    int q = tid & 15;
    float4 v;
    if (r < BATCH) v = uw[(size_t)users[r] * 16 + q];
    else           v = iw[(size_t)items[r - BATCH] * 16 + q];
    accb[tid] = v;
}

// ---------------------------------------------------------------------------
// Batch accumulator add from full node table (layers 1,2).
// ---------------------------------------------------------------------------
__global__ void batch_add(const float4* __restrict__ emb,
                          const int* __restrict__ users,
                          const int* __restrict__ items,
                          float4* __restrict__ accb) {
    int tid = blockIdx.x * blockDim.x + threadIdx.x;
    const int total = 2 * BATCH * (DIM / 4);
    if (tid >= total) return;
    int r = tid >> 4;
    int q = tid & 15;
    int node = (r < BATCH) ? users[r] : (N_USERS + items[r - BATCH]);
    float4 v = emb[(size_t)node * 16 + q];
    float4 a = accb[tid];
    a.x += v.x; a.y += v.y; a.z += v.z; a.w += v.w;
    accb[tid] = a;
}

// ---------------------------------------------------------------------------
// Final dot: out[b] = (accb[b] . accb[BATCH+b]) / 16
// ---------------------------------------------------------------------------
__global__ void final_dot(const float* __restrict__ accb,
                          float* __restrict__ out) {
    int b = blockIdx.x * 4 + (threadIdx.x >> 6);
    int lane = threadIdx.x & 63;
    if (b >= BATCH) return;
    float pu = accb[(size_t)b * 64 + lane];
    float pi = accb[(size_t)(BATCH + b) * 64 + lane];
    float p = pu * pi;
    #pragma unroll
    for (int off = 32; off > 0; off >>= 1)
        p += __shfl_down(p, off, 64);
    if (lane == 0) out[b] = p * (1.0f / 16.0f);
}

extern "C" void kernel_launch(void* const* d_in, const int* in_sizes, int n_in,
                              void* d_out, int out_size, void* d_ws, size_t ws_size,
                              hipStream_t stream) {
    const float* uw   = (const float*)d_in[0];
    const float* iw   = (const float*)d_in[1];
    const float* tw   = (const float*)d_in[2];
    const float* vals = (const float*)d_in[3];
    const int*   row  = (const int*)d_in[4];
    const int*   col  = (const int*)d_in[5];
    const int*   users= (const int*)d_in[6];
    const int*   items= (const int*)d_in[7];
    float* out = (float*)d_out;

    // ---- workspace layout ----
    char* ws = (char*)d_ws;
    const size_t NODE_F = (size_t)N_NODES * DIM;       // 9,664,000 floats
    float* A      = (float*)ws;  ws += NODE_F * 4;
    float* B      = (float*)ws;  ws += NODE_F * 4;     // also cvtmp staging
    float* ACCB   = (float*)ws;  ws += (size_t)2 * BATCH * DIM * 4;
    int*   bcnt   = (int*)ws;    ws += (size_t)NB * 4;
    int*   bptr   = (int*)ws;    ws += (size_t)(NB + 1) * 4;
    int*   rowptr = (int*)ws;    ws += (size_t)(N_NODES + 1) * 4;
    int*   hcnt   = (int*)ws;    ws += (size_t)NPART * NB * 4;   // 2.42 MB
    int2*  cv     = (int2*)ws;   ws += (size_t)NNZ * 8;
    int2*  cvtmp  = (int2*)B;    // 32 MB staging inside B's 38.7 MB; consumed
                                 // by bucket_sort before spmm1 writes B

    const int node_v4  = N_NODES * (DIM / 4);
    const int batch_v4 = 2 * BATCH * (DIM / 4);

    // ---- layer-0 embedding + batch accumulator init FIRST, so nothing
    //      intervenes between bucket_sort's cv writes and spmm1's reads ----
    concat_init<<<(node_v4 + 255) / 256, 256, 0, stream>>>(
        (const float4*)uw, (const float4*)iw, (const float4*)tw, (float4*)A);
    batch_init<<<(batch_v4 + 255) / 256, 256, 0, stream>>>(
        (const float4*)uw, (const float4*)iw, users, items, (float4*)ACCB);

    // ---- atomic-free bucketed partition + bucket-local sort -> CSR ----
    part_count<<<NPART, 256, 0, stream>>>(row, hcnt);
    part_scanA<<<(NB + 3) / 4, 256, 0, stream>>>(hcnt, bcnt);
    part_scanB<<<1, 1024, 0, stream>>>(bcnt, bptr, rowptr);
    part_scatter<<<NPART, 256, 0, stream>>>(row, col, vals, hcnt, bptr, cvtmp);
    bucket_sort<<<NB, 256, 0, stream>>>(bptr, (const long long*)cvtmp, cv, rowptr);

    // ---- layers 1,2: full SpMM (swizzled); layer 3: batch rows only ----
    const int spmm_blocks = ((NB + 7) / 8) * 256;   // 148*256 = 37888
    spmm_csr<<<spmm_blocks, 256, 0, stream>>>(rowptr, cv, A, B);
    batch_add<<<(batch_v4 + 255) / 256, 256, 0, stream>>>(
        (const float4*)B, users, items, (float4*)ACCB);
    spmm_csr<<<spmm_blocks, 256, 0, stream>>>(rowptr, cv, B, A);
    batch_add<<<(batch_v4 + 255) / 256, 256, 0, stream>>>(
        (const float4*)A, users, items, (float4*)ACCB);
    spmm_batch<<<(2 * BATCH + 3) / 4, 256, 0, stream>>>(
        rowptr, cv, A, users, items, ACCB);

    final_dot<<<(BATCH + 3) / 4, 256, 0, stream>>>(ACCB, out);
}

// Round 11
// 580.381 us; speedup vs baseline: 1.2816x; 1.0776x over previous
//
#include <hip/hip_runtime.h>
#include <hip/hip_fp16.h>

#define N_USERS 100000
#define N_ITEMS 50000
#define N_TOPICS 1000
#define N_NODES (N_USERS + N_ITEMS + N_TOPICS)   // 151000
#define DIM 64
#define NNZ 4000000
#define BATCH 16384

#define BROWS 128                                 // rows per bucket
#define NB ((N_NODES + BROWS - 1) / BROWS)        // 1180 buckets
#define NPART 512                                 // partition blocks
#define CHUNK ((NNZ + NPART - 1) / NPART)         // 7813 edges per block
#define SEGCAP 4608                               // LDS seg capacity (36 KB)

// ---------------------------------------------------------------------------
// Build X0 = concat(user_w, item_w, topic_w) in FP16. One float4 (4 dims)
// per thread, stored as two __half2.
// ---------------------------------------------------------------------------
__global__ void concat_init(const float4* __restrict__ uw,
                            const float4* __restrict__ iw,
                            const float4* __restrict__ tw,
                            __half2* __restrict__ x0) {
    int tid = blockIdx.x * blockDim.x + threadIdx.x;   // node*16 + q
    const int total = N_NODES * (DIM / 4);
    if (tid >= total) return;
    int node = tid >> 4;
    int q = tid & 15;
    float4 v;
    if (node < N_USERS)                v = uw[node * 16 + q];
    else if (node < N_USERS + N_ITEMS) v = iw[(node - N_USERS) * 16 + q];
    else                               v = tw[(node - N_USERS - N_ITEMS) * 16 + q];
    x0[tid * 2]     = __floats2half2_rn(v.x, v.y);
    x0[tid * 2 + 1] = __floats2half2_rn(v.z, v.w);
}

// ---------------------------------------------------------------------------
// Partition phase 1: per-block bucket histogram of its contiguous chunk.
// ---------------------------------------------------------------------------
__global__ void __launch_bounds__(256)
part_count(const int* __restrict__ row, int* __restrict__ hcnt) {
    __shared__ int h[NB];
    const int g = blockIdx.x;
    const int t = threadIdx.x;
    for (int i = t; i < NB; i += 256) h[i] = 0;
    __syncthreads();
    int e0 = g * CHUNK;
    int e1 = e0 + CHUNK; if (e1 > NNZ) e1 = NNZ;
    for (int e = e0 + t; e < e1; e += 256) {
        int r = __builtin_nontemporal_load(&row[e]);
        atomicAdd(&h[r >> 7], 1);
    }
    __syncthreads();
    int* dst = hcnt + (size_t)g * NB;
    for (int i = t; i < NB; i += 256) dst[i] = h[i];
}

// ---------------------------------------------------------------------------
// Partition phase 2a: per-bucket exclusive scan across the NPART blocks.
// ---------------------------------------------------------------------------
__global__ void part_scanA(int* __restrict__ hcnt, int* __restrict__ bcnt) {
    int b = blockIdx.x * 4 + (threadIdx.x >> 6);
    int lane = threadIdx.x & 63;
    if (b >= NB) return;
    int carry = 0;
    for (int base = 0; base < NPART; base += 64) {
        int g = base + lane;
        int v = hcnt[(size_t)g * NB + b];
        int x = v;
        #pragma unroll
        for (int off = 1; off < 64; off <<= 1) {
            int y = __shfl_up(x, off, 64);
            if (lane >= off) x += y;
        }
        int tot = __shfl(x, 63, 64);
        hcnt[(size_t)g * NB + b] = carry + x - v;
        carry += tot;
    }
    if (lane == 0) bcnt[b] = carry;
}

// ---------------------------------------------------------------------------
// Partition phase 2b: exclusive scan over NB bucket totals (single block).
// ---------------------------------------------------------------------------
__global__ void part_scanB(const int* __restrict__ bcnt,
                           int* __restrict__ bptr,
                           int* __restrict__ rowptr) {
    __shared__ int wsum[16];
    __shared__ int carry_s;
    const int t = threadIdx.x;
    const int lane = t & 63;
    const int wid = t >> 6;
    if (t == 0) carry_s = 0;
    __syncthreads();
    for (int base = 0; base < NB; base += 1024) {
        int i = base + t;
        int v = (i < NB) ? bcnt[i] : 0;
        int x = v;
        #pragma unroll
        for (int off = 1; off < 64; off <<= 1) {
            int y = __shfl_up(x, off, 64);
            if (lane >= off) x += y;
        }
        if (lane == 63) wsum[wid] = x;
        __syncthreads();
        int wbase = 0;
        for (int w = 0; w < wid; ++w) wbase += wsum[w];
        int excl = carry_s + wbase + (x - v);
        if (i < NB) bptr[i] = excl;
        __syncthreads();
        if (t == 1023) carry_s = excl + v;
        __syncthreads();
    }
    if (t == 0) { bptr[NB] = NNZ; rowptr[N_NODES] = NNZ; }
}

// ---------------------------------------------------------------------------
// Partition phase 3: atomic-free scatter via per-(block,bucket) offsets.
// ---------------------------------------------------------------------------
__global__ void __launch_bounds__(256)
part_scatter(const int* __restrict__ row,
             const int* __restrict__ col,
             const float* __restrict__ vals,
             const int* __restrict__ hcnt,
             const int* __restrict__ bptr,
             int2* __restrict__ cvtmp) {
    __shared__ int cur[NB];
    const int g = blockIdx.x;
    const int t = threadIdx.x;
    const int* hoff = hcnt + (size_t)g * NB;
    for (int i = t; i < NB; i += 256) cur[i] = bptr[i] + hoff[i];
    __syncthreads();
    int e0 = g * CHUNK;
    int e1 = e0 + CHUNK; if (e1 > NNZ) e1 = NNZ;
    for (int e = e0 + t; e < e1; e += 256) {
        int r = __builtin_nontemporal_load(&row[e]);
        int c = __builtin_nontemporal_load(&col[e]);
        float v = __builtin_nontemporal_load(&vals[e]);
        int p = atomicAdd(&cur[r >> 7], 1);
        cvtmp[p] = make_int2(((r & (BROWS - 1)) << 18) | c, __float_as_int(v));
    }
}

// ---------------------------------------------------------------------------
// Bucket-local counting sort -> row-sorted CSR (cv) + rowptr.
// Segment staged in LDS once (<=36 KB); normal stores for cv.
// ---------------------------------------------------------------------------
__global__ void __launch_bounds__(256)
bucket_sort(const int* __restrict__ bptr,
            const long long* __restrict__ cvtmp,
            int2* __restrict__ cv,
            int* __restrict__ rowptr) {
    __shared__ int2 seg[SEGCAP];     // 36 KB
    __shared__ int cnt[BROWS];
    __shared__ int cur[BROWS];
    const int t = threadIdx.x;
    const int b = blockIdx.x;
    const int beg = bptr[b];
    const int end = bptr[b + 1];
    const int n = end - beg;

    for (int i = t; i < BROWS; i += 256) cnt[i] = 0;
    const bool lds_path = (n <= SEGCAP);

    if (lds_path) {
        for (int j = t; j < n; j += 256) {
            long long e = cvtmp[beg + j];
            seg[j] = make_int2((int)e, (int)(e >> 32));
        }
    }
    __syncthreads();

    // pass 1: per-row counts
    if (lds_path) {
        for (int j = t; j < n; j += 256)
            atomicAdd(&cnt[(seg[j].x >> 18) & (BROWS - 1)], 1);
    } else {
        for (int j = beg + t; j < end; j += 256) {
            long long e = cvtmp[j];
            atomicAdd(&cnt[((int)e >> 18) & (BROWS - 1)], 1);
        }
    }
    __syncthreads();

    // exclusive scan of 128 counts on wave 0; also emit rowptr
    if (t < 64) {
        int lane = t;
        int v0 = cnt[lane];
        int v1 = cnt[64 + lane];
        int x0 = v0;
        #pragma unroll
        for (int off = 1; off < 64; off <<= 1) {
            int y = __shfl_up(x0, off, 64);
            if (lane >= off) x0 += y;
        }
        int tot0 = __shfl(x0, 63, 64);
        int x1 = v1;
        #pragma unroll
        for (int off = 1; off < 64; off <<= 1) {
            int y = __shfl_up(x1, off, 64);
            if (lane >= off) x1 += y;
        }
        x1 += tot0;
        int e0 = x0 - v0;
        int e1 = x1 - v1;
        cur[lane] = e0;
        cur[64 + lane] = e1;
        int rowbase = b * BROWS;
        if (rowbase + lane < N_NODES)      rowptr[rowbase + lane] = beg + e0;
        if (rowbase + 64 + lane < N_NODES) rowptr[rowbase + 64 + lane] = beg + e1;
    }
    __syncthreads();

    // pass 2: scatter into row-sorted order, strip row bits
    if (lds_path) {
        for (int j = t; j < n; j += 256) {
            int2 e = seg[j];
            int p = atomicAdd(&cur[(e.x >> 18) & (BROWS - 1)], 1);
            cv[beg + p] = make_int2(e.x & 0x3FFFF, e.y);
        }
    } else {
        for (int j = beg + t; j < end; j += 256) {
            long long e = cvtmp[j];
            int lo = (int)e;
            int hi = (int)(e >> 32);
            int p = atomicAdd(&cur[(lo >> 18) & (BROWS - 1)], 1);
            cv[beg + p] = make_int2(lo & 0x3FFFF, hi);
        }
    }
}

// ---------------------------------------------------------------------------
// SpMM over CSR, FP16 node tables: one 64-lane wave per row, lane = dim,
// fp32 register accumulation, fp16 store. Gather = 128B/edge (half of fp32).
// Swizzled block->row mapping matches bucket_sort's XCD placement.
// ---------------------------------------------------------------------------
__global__ void spmm_csr(const int* __restrict__ rowptr,
                         const int2* __restrict__ cv,
                         const __half* __restrict__ x,
                         __half* __restrict__ y) {
    int blk = blockIdx.x;
    int bucket = (blk >> 8) * 8 + (blk & 7);
    int sub = (blk & 255) >> 3;
    int r = bucket * BROWS + sub * 4 + (threadIdx.x >> 6);
    int lane = threadIdx.x & 63;
    if (r >= N_NODES) return;
    int beg = rowptr[r];
    int end = rowptr[r + 1];
    float acc0 = 0.0f, acc1 = 0.0f;
    int j = beg;
    for (; j + 7 < end; j += 8) {
        #pragma unroll
        for (int k = 0; k < 8; k += 2) {
            int2 ea = cv[j + k];
            int2 eb = cv[j + k + 1];
            float xa = __half2float(x[(size_t)ea.x * 64 + lane]);
            float xb = __half2float(x[(size_t)eb.x * 64 + lane]);
            acc0 = fmaf(__int_as_float(ea.y), xa, acc0);
            acc1 = fmaf(__int_as_float(eb.y), xb, acc1);
        }
    }
    for (; j < end; ++j) {
        int2 e = cv[j];
        acc0 = fmaf(__int_as_float(e.y),
                    __half2float(x[(size_t)e.x * 64 + lane]), acc0);
    }
    y[(size_t)r * 64 + lane] = __float2half_rn(acc0 + acc1);
}

// ---------------------------------------------------------------------------
// Layer-3 SpMM restricted to batch rows (~870K edges), fp16 gather,
// fp32 accumulation straight into ACCB.
// ---------------------------------------------------------------------------
__global__ void spmm_batch(const int* __restrict__ rowptr,
                           const int2* __restrict__ cv,
                           const __half* __restrict__ x,
                           const int* __restrict__ users,
                           const int* __restrict__ items,
                           float* __restrict__ accb) {
    int b = blockIdx.x * 4 + (threadIdx.x >> 6);
    int lane = threadIdx.x & 63;
    if (b >= 2 * BATCH) return;
    int r = (b < BATCH) ? users[b] : (N_USERS + items[b - BATCH]);
    int beg = rowptr[r];
    int end = rowptr[r + 1];
    float acc0 = 0.0f, acc1 = 0.0f;
    int j = beg;
    for (; j + 7 < end; j += 8) {
        #pragma unroll
        for (int k = 0; k < 8; k += 2) {
            int2 ea = cv[j + k];
            int2 eb = cv[j + k + 1];
            float xa = __half2float(x[(size_t)ea.x * 64 + lane]);
            float xb = __half2float(x[(size_t)eb.x * 64 + lane]);
            acc0 = fmaf(__int_as_float(ea.y), xa, acc0);
            acc1 = fmaf(__int_as_float(eb.y), xb, acc1);
        }
    }
    for (; j < end; ++j) {
        int2 e = cv[j];
        acc0 = fmaf(__int_as_float(e.y),
                    __half2float(x[(size_t)e.x * 64 + lane]), acc0);
    }
    size_t o = (size_t)b * 64 + lane;
    accb[o] += acc0 + acc1;
}

// ---------------------------------------------------------------------------
// Batch accumulator init (fp32 weights -> fp32 ACCB; layer-0 term exact).
// ---------------------------------------------------------------------------
__global__ void batch_init(const float4* __restrict__ uw,
                           const float4* __restrict__ iw,
                           const int* __restrict__ users,
                           const int* __restrict__ items,
                           float4* __restrict__ accb) {
    int tid = blockIdx.x * blockDim.x + threadIdx.x;   // row*16 + q
    const int total = 2 * BATCH * (DIM / 4);
    if (tid >= total) return;
    int r = tid >> 4;
    int q = tid & 15;
    float4 v;
    if (r < BATCH) v = uw[(size_t)users[r] * 16 + q];
    else           v = iw[(size_t)items[r - BATCH] * 16 + q];
    accb[tid] = v;
}

// ---------------------------------------------------------------------------
// Batch accumulator add from fp16 node table (layers 1,2).
// ---------------------------------------------------------------------------
__global__ void batch_add(const __half* __restrict__ emb,
                          const int* __restrict__ users,
                          const int* __restrict__ items,
                          float4* __restrict__ accb) {
    int tid = blockIdx.x * blockDim.x + threadIdx.x;
    const int total = 2 * BATCH * (DIM / 4);
    if (tid >= total) return;
    int r = tid >> 4;
    int q = tid & 15;
    int node = (r < BATCH) ? users[r] : (N_USERS + items[r - BATCH]);
    const __half2* e2 = (const __half2*)(emb + (size_t)node * 64 + q * 4);
    float2 lo = __half22float2(e2[0]);
    float2 hi = __half22float2(e2[1]);
    float4 a = accb[tid];
    a.x += lo.x; a.y += lo.y; a.z += hi.x; a.w += hi.y;
    accb[tid] = a;
}

// ---------------------------------------------------------------------------
// Final dot: out[b] = (accb[b] . accb[BATCH+b]) / 16
// ---------------------------------------------------------------------------
__global__ void final_dot(const float* __restrict__ accb,
                          float* __restrict__ out) {
    int b = blockIdx.x * 4 + (threadIdx.x >> 6);
    int lane = threadIdx.x & 63;
    if (b >= BATCH) return;
    float pu = accb[(size_t)b * 64 + lane];
    float pi = accb[(size_t)(BATCH + b) * 64 + lane];
    float p = pu * pi;
    #pragma unroll
    for (int off = 32; off > 0; off >>= 1)
        p += __shfl_down(p, off, 64);
    if (lane == 0) out[b] = p * (1.0f / 16.0f);
}

extern "C" void kernel_launch(void* const* d_in, const int* in_sizes, int n_in,
                              void* d_out, int out_size, void* d_ws, size_t ws_size,
                              hipStream_t stream) {
    const float* uw   = (const float*)d_in[0];
    const float* iw   = (const float*)d_in[1];
    const float* tw   = (const float*)d_in[2];
    const float* vals = (const float*)d_in[3];
    const int*   row  = (const int*)d_in[4];
    const int*   col  = (const int*)d_in[5];
    const int*   users= (const int*)d_in[6];
    const int*   items= (const int*)d_in[7];
    float* out = (float*)d_out;

    // ---- workspace layout (no aliasing; ~114 MB total) ----
    char* ws = (char*)d_ws;
    const size_t NODE_F = (size_t)N_NODES * DIM;       // 9,664,000 elements
    __half* A     = (__half*)ws; ws += NODE_F * 2;     // 19.33 MB
    __half* B     = (__half*)ws; ws += NODE_F * 2;     // 19.33 MB
    float* ACCB   = (float*)ws;  ws += (size_t)2 * BATCH * DIM * 4;
    int*   bcnt   = (int*)ws;    ws += (size_t)NB * 4;
    int*   bptr   = (int*)ws;    ws += (size_t)(NB + 1) * 4;
    int*   rowptr = (int*)ws;    ws += (size_t)(N_NODES + 1) * 4;
    int*   hcnt   = (int*)ws;    ws += (size_t)NPART * NB * 4;   // 2.42 MB
    int2*  cv     = (int2*)ws;   ws += (size_t)NNZ * 8;          // 32 MB
    int2*  cvtmp  = (int2*)ws;   ws += (size_t)NNZ * 8;          // 32 MB

    const int node_v4  = N_NODES * (DIM / 4);
    const int batch_v4 = 2 * BATCH * (DIM / 4);

    // ---- layer-0 embedding (fp16) + batch accumulator init (fp32) ----
    concat_init<<<(node_v4 + 255) / 256, 256, 0, stream>>>(
        (const float4*)uw, (const float4*)iw, (const float4*)tw, (__half2*)A);
    batch_init<<<(batch_v4 + 255) / 256, 256, 0, stream>>>(
        (const float4*)uw, (const float4*)iw, users, items, (float4*)ACCB);

    // ---- atomic-free bucketed partition + bucket-local sort -> CSR ----
    part_count<<<NPART, 256, 0, stream>>>(row, hcnt);
    part_scanA<<<(NB + 3) / 4, 256, 0, stream>>>(hcnt, bcnt);
    part_scanB<<<1, 1024, 0, stream>>>(bcnt, bptr, rowptr);
    part_scatter<<<NPART, 256, 0, stream>>>(row, col, vals, hcnt, bptr, cvtmp);
    bucket_sort<<<NB, 256, 0, stream>>>(bptr, (const long long*)cvtmp, cv, rowptr);

    // ---- layers 1,2: full SpMM (fp16 tables); layer 3: batch rows only ----
    const int spmm_blocks = ((NB + 7) / 8) * 256;   // 148*256 = 37888
    spmm_csr<<<spmm_blocks, 256, 0, stream>>>(rowptr, cv, A, B);
    batch_add<<<(batch_v4 + 255) / 256, 256, 0, stream>>>(
        B, users, items, (float4*)ACCB);
    spmm_csr<<<spmm_blocks, 256, 0, stream>>>(rowptr, cv, B, A);
    batch_add<<<(batch_v4 + 255) / 256, 256, 0, stream>>>(
        A, users, items, (float4*)ACCB);
    spmm_batch<<<(2 * BATCH + 3) / 4, 256, 0, stream>>>(
        rowptr, cv, A, users, items, ACCB);

    final_dot<<<(BATCH + 3) / 4, 256, 0, stream>>>(ACCB, out);
}

// Round 12
// 529.058 us; speedup vs baseline: 1.4059x; 1.0970x over previous
//
#include <hip/hip_runtime.h>
#include <hip/hip_fp16.h>

#define N_USERS 100000
#define N_ITEMS 50000
#define N_TOPICS 1000
#define N_NODES (N_USERS + N_ITEMS + N_TOPICS)   // 151000
#define DIM 64
#define NNZ 4000000
#define BATCH 16384

#define BROWS 128                                 // rows per bucket
#define NB ((N_NODES + BROWS - 1) / BROWS)        // 1180 buckets
#define NPART 512                                 // partition blocks
#define CHUNK ((NNZ + NPART - 1) / NPART)         // 7813 edges per block
#define SEGCAP 4608                               // LDS seg capacity (36 KB)

// ---------------------------------------------------------------------------
// Build X0 = concat(user_w, item_w, topic_w) in FP16. One float4 (4 dims)
// per thread, stored as two __half2.
// ---------------------------------------------------------------------------
__global__ void concat_init(const float4* __restrict__ uw,
                            const float4* __restrict__ iw,
                            const float4* __restrict__ tw,
                            __half2* __restrict__ x0) {
    int tid = blockIdx.x * blockDim.x + threadIdx.x;   // node*16 + q
    const int total = N_NODES * (DIM / 4);
    if (tid >= total) return;
    int node = tid >> 4;
    int q = tid & 15;
    float4 v;
    if (node < N_USERS)                v = uw[node * 16 + q];
    else if (node < N_USERS + N_ITEMS) v = iw[(node - N_USERS) * 16 + q];
    else                               v = tw[(node - N_USERS - N_ITEMS) * 16 + q];
    x0[tid * 2]     = __floats2half2_rn(v.x, v.y);
    x0[tid * 2 + 1] = __floats2half2_rn(v.z, v.w);
}

// ---------------------------------------------------------------------------
// Partition phase 1: per-block bucket histogram of its contiguous chunk.
// ---------------------------------------------------------------------------
__global__ void __launch_bounds__(256)
part_count(const int* __restrict__ row, int* __restrict__ hcnt) {
    __shared__ int h[NB];
    const int g = blockIdx.x;
    const int t = threadIdx.x;
    for (int i = t; i < NB; i += 256) h[i] = 0;
    __syncthreads();
    int e0 = g * CHUNK;
    int e1 = e0 + CHUNK; if (e1 > NNZ) e1 = NNZ;
    for (int e = e0 + t; e < e1; e += 256) {
        int r = __builtin_nontemporal_load(&row[e]);
        atomicAdd(&h[r >> 7], 1);
    }
    __syncthreads();
    int* dst = hcnt + (size_t)g * NB;
    for (int i = t; i < NB; i += 256) dst[i] = h[i];
}

// ---------------------------------------------------------------------------
// Partition phase 2a: per-bucket exclusive scan across the NPART blocks.
// ---------------------------------------------------------------------------
__global__ void part_scanA(int* __restrict__ hcnt, int* __restrict__ bcnt) {
    int b = blockIdx.x * 4 + (threadIdx.x >> 6);
    int lane = threadIdx.x & 63;
    if (b >= NB) return;
    int carry = 0;
    for (int base = 0; base < NPART; base += 64) {
        int g = base + lane;
        int v = hcnt[(size_t)g * NB + b];
        int x = v;
        #pragma unroll
        for (int off = 1; off < 64; off <<= 1) {
            int y = __shfl_up(x, off, 64);
            if (lane >= off) x += y;
        }
        int tot = __shfl(x, 63, 64);
        hcnt[(size_t)g * NB + b] = carry + x - v;
        carry += tot;
    }
    if (lane == 0) bcnt[b] = carry;
}

// ---------------------------------------------------------------------------
// Partition phase 2b: exclusive scan over NB bucket totals (single block).
// ---------------------------------------------------------------------------
__global__ void part_scanB(const int* __restrict__ bcnt,
                           int* __restrict__ bptr,
                           int* __restrict__ rowptr) {
    __shared__ int wsum[16];
    __shared__ int carry_s;
    const int t = threadIdx.x;
    const int lane = t & 63;
    const int wid = t >> 6;
    if (t == 0) carry_s = 0;
    __syncthreads();
    for (int base = 0; base < NB; base += 1024) {
        int i = base + t;
        int v = (i < NB) ? bcnt[i] : 0;
        int x = v;
        #pragma unroll
        for (int off = 1; off < 64; off <<= 1) {
            int y = __shfl_up(x, off, 64);
            if (lane >= off) x += y;
        }
        if (lane == 63) wsum[wid] = x;
        __syncthreads();
        int wbase = 0;
        for (int w = 0; w < wid; ++w) wbase += wsum[w];
        int excl = carry_s + wbase + (x - v);
        if (i < NB) bptr[i] = excl;
        __syncthreads();
        if (t == 1023) carry_s = excl + v;
        __syncthreads();
    }
    if (t == 0) { bptr[NB] = NNZ; rowptr[N_NODES] = NNZ; }
}

// ---------------------------------------------------------------------------
// Partition phase 3: atomic-free scatter via per-(block,bucket) offsets.
// ---------------------------------------------------------------------------
__global__ void __launch_bounds__(256)
part_scatter(const int* __restrict__ row,
             const int* __restrict__ col,
             const float* __restrict__ vals,
             const int* __restrict__ hcnt,
             const int* __restrict__ bptr,
             int2* __restrict__ cvtmp) {
    __shared__ int cur[NB];
    const int g = blockIdx.x;
    const int t = threadIdx.x;
    const int* hoff = hcnt + (size_t)g * NB;
    for (int i = t; i < NB; i += 256) cur[i] = bptr[i] + hoff[i];
    __syncthreads();
    int e0 = g * CHUNK;
    int e1 = e0 + CHUNK; if (e1 > NNZ) e1 = NNZ;
    for (int e = e0 + t; e < e1; e += 256) {
        int r = __builtin_nontemporal_load(&row[e]);
        int c = __builtin_nontemporal_load(&col[e]);
        float v = __builtin_nontemporal_load(&vals[e]);
        int p = atomicAdd(&cur[r >> 7], 1);
        cvtmp[p] = make_int2(((r & (BROWS - 1)) << 18) | c, __float_as_int(v));
    }
}

// ---------------------------------------------------------------------------
// Bucket-local counting sort -> row-sorted CSR (cv) + rowptr.
// Segment staged in LDS once (<=36 KB); normal stores for cv.
// ---------------------------------------------------------------------------
__global__ void __launch_bounds__(256)
bucket_sort(const int* __restrict__ bptr,
            const long long* __restrict__ cvtmp,
            int2* __restrict__ cv,
            int* __restrict__ rowptr) {
    __shared__ int2 seg[SEGCAP];     // 36 KB
    __shared__ int cnt[BROWS];
    __shared__ int cur[BROWS];
    const int t = threadIdx.x;
    const int b = blockIdx.x;
    const int beg = bptr[b];
    const int end = bptr[b + 1];
    const int n = end - beg;

    for (int i = t; i < BROWS; i += 256) cnt[i] = 0;
    const bool lds_path = (n <= SEGCAP);

    if (lds_path) {
        for (int j = t; j < n; j += 256) {
            long long e = cvtmp[beg + j];
            seg[j] = make_int2((int)e, (int)(e >> 32));
        }
    }
    __syncthreads();

    // pass 1: per-row counts
    if (lds_path) {
        for (int j = t; j < n; j += 256)
            atomicAdd(&cnt[(seg[j].x >> 18) & (BROWS - 1)], 1);
    } else {
        for (int j = beg + t; j < end; j += 256) {
            long long e = cvtmp[j];
            atomicAdd(&cnt[((int)e >> 18) & (BROWS - 1)], 1);
        }
    }
    __syncthreads();

    // exclusive scan of 128 counts on wave 0; also emit rowptr
    if (t < 64) {
        int lane = t;
        int v0 = cnt[lane];
        int v1 = cnt[64 + lane];
        int x0 = v0;
        #pragma unroll
        for (int off = 1; off < 64; off <<= 1) {
            int y = __shfl_up(x0, off, 64);
            if (lane >= off) x0 += y;
        }
        int tot0 = __shfl(x0, 63, 64);
        int x1 = v1;
        #pragma unroll
        for (int off = 1; off < 64; off <<= 1) {
            int y = __shfl_up(x1, off, 64);
            if (lane >= off) x1 += y;
        }
        x1 += tot0;
        int e0 = x0 - v0;
        int e1 = x1 - v1;
        cur[lane] = e0;
        cur[64 + lane] = e1;
        int rowbase = b * BROWS;
        if (rowbase + lane < N_NODES)      rowptr[rowbase + lane] = beg + e0;
        if (rowbase + 64 + lane < N_NODES) rowptr[rowbase + 64 + lane] = beg + e1;
    }
    __syncthreads();

    // pass 2: scatter into row-sorted order, strip row bits
    if (lds_path) {
        for (int j = t; j < n; j += 256) {
            int2 e = seg[j];
            int p = atomicAdd(&cur[(e.x >> 18) & (BROWS - 1)], 1);
            cv[beg + p] = make_int2(e.x & 0x3FFFF, e.y);
        }
    } else {
        for (int j = beg + t; j < end; j += 256) {
            long long e = cvtmp[j];
            int lo = (int)e;
            int hi = (int)(e >> 32);
            int p = atomicAdd(&cur[(lo >> 18) & (BROWS - 1)], 1);
            cv[beg + p] = make_int2(lo & 0x3FFFF, hi);
        }
    }
}

// ---------------------------------------------------------------------------
// SpMM over CSR, FP16 tables, half-wave-per-edge: lanes 0-31 process even
// edges, lanes 32-63 odd edges; lane d=lane&31 holds dim-pair (2d,2d+1) as
// __half2 (4B/lane -> one gather inst = 2 edges x 128B = 256B full width).
// fp32 accumulation; cross-half shfl combine; lanes<32 store the row.
// ---------------------------------------------------------------------------
__global__ void spmm_csr(const int* __restrict__ rowptr,
                         const int2* __restrict__ cv,
                         const __half2* __restrict__ x2,
                         __half2* __restrict__ y2) {
    int blk = blockIdx.x;
    int bucket = (blk >> 8) * 8 + (blk & 7);
    int sub = (blk & 255) >> 3;
    int r = bucket * BROWS + sub * 4 + (threadIdx.x >> 6);
    if (r >= N_NODES) return;
    int lane = threadIdx.x & 63;
    int half = lane >> 5;
    int d = lane & 31;
    int beg = rowptr[r];
    int end = rowptr[r + 1];
    float ax0 = 0.0f, ay0 = 0.0f, ax1 = 0.0f, ay1 = 0.0f;
    int j = beg + half;                 // this half's edge stream, stride 2
    for (; j + 6 < end; j += 8) {       // 4 edges per half per iter
        int2 e0 = cv[j];
        int2 e1 = cv[j + 2];
        int2 e2 = cv[j + 4];
        int2 e3 = cv[j + 6];
        __half2 h0 = x2[(size_t)e0.x * 32 + d];
        __half2 h1 = x2[(size_t)e1.x * 32 + d];
        __half2 h2 = x2[(size_t)e2.x * 32 + d];
        __half2 h3 = x2[(size_t)e3.x * 32 + d];
        float2 f0 = __half22float2(h0);
        float2 f1 = __half22float2(h1);
        float2 f2 = __half22float2(h2);
        float2 f3 = __half22float2(h3);
        float v0 = __int_as_float(e0.y);
        float v1 = __int_as_float(e1.y);
        float v2 = __int_as_float(e2.y);
        float v3 = __int_as_float(e3.y);
        ax0 = fmaf(v0, f0.x, ax0); ay0 = fmaf(v0, f0.y, ay0);
        ax1 = fmaf(v1, f1.x, ax1); ay1 = fmaf(v1, f1.y, ay1);
        ax0 = fmaf(v2, f2.x, ax0); ay0 = fmaf(v2, f2.y, ay0);
        ax1 = fmaf(v3, f3.x, ax1); ay1 = fmaf(v3, f3.y, ay1);
    }
    for (; j < end; j += 2) {
        int2 e = cv[j];
        float2 f = __half22float2(x2[(size_t)e.x * 32 + d]);
        float v = __int_as_float(e.y);
        ax0 = fmaf(v, f.x, ax0); ay0 = fmaf(v, f.y, ay0);
    }
    float ax = ax0 + ax1;
    float ay = ay0 + ay1;
    ax += __shfl_down(ax, 32, 64);
    ay += __shfl_down(ay, 32, 64);
    if (lane < 32) y2[(size_t)r * 32 + d] = __floats2half2_rn(ax, ay);
}

// ---------------------------------------------------------------------------
// Layer-3 SpMM restricted to batch rows (~870K edges), same half-wave
// structure, fp32 accumulation straight into ACCB (float2 RMW).
// ---------------------------------------------------------------------------
__global__ void spmm_batch(const int* __restrict__ rowptr,
                           const int2* __restrict__ cv,
                           const __half2* __restrict__ x2,
                           const int* __restrict__ users,
                           const int* __restrict__ items,
                           float* __restrict__ accb) {
    int b = blockIdx.x * 4 + (threadIdx.x >> 6);
    if (b >= 2 * BATCH) return;
    int lane = threadIdx.x & 63;
    int half = lane >> 5;
    int d = lane & 31;
    int r = (b < BATCH) ? users[b] : (N_USERS + items[b - BATCH]);
    int beg = rowptr[r];
    int end = rowptr[r + 1];
    float ax0 = 0.0f, ay0 = 0.0f, ax1 = 0.0f, ay1 = 0.0f;
    int j = beg + half;
    for (; j + 6 < end; j += 8) {
        int2 e0 = cv[j];
        int2 e1 = cv[j + 2];
        int2 e2 = cv[j + 4];
        int2 e3 = cv[j + 6];
        __half2 h0 = x2[(size_t)e0.x * 32 + d];
        __half2 h1 = x2[(size_t)e1.x * 32 + d];
        __half2 h2 = x2[(size_t)e2.x * 32 + d];
        __half2 h3 = x2[(size_t)e3.x * 32 + d];
        float2 f0 = __half22float2(h0);
        float2 f1 = __half22float2(h1);
        float2 f2 = __half22float2(h2);
        float2 f3 = __half22float2(h3);
        float v0 = __int_as_float(e0.y);
        float v1 = __int_as_float(e1.y);
        float v2 = __int_as_float(e2.y);
        float v3 = __int_as_float(e3.y);
        ax0 = fmaf(v0, f0.x, ax0); ay0 = fmaf(v0, f0.y, ay0);
        ax1 = fmaf(v1, f1.x, ax1); ay1 = fmaf(v1, f1.y, ay1);
        ax0 = fmaf(v2, f2.x, ax0); ay0 = fmaf(v2, f2.y, ay0);
        ax1 = fmaf(v3, f3.x, ax1); ay1 = fmaf(v3, f3.y, ay1);
    }
    for (; j < end; j += 2) {
        int2 e = cv[j];
        float2 f = __half22float2(x2[(size_t)e.x * 32 + d]);
        float v = __int_as_float(e.y);
        ax0 = fmaf(v, f.x, ax0); ay0 = fmaf(v, f.y, ay0);
    }
    float ax = ax0 + ax1;
    float ay = ay0 + ay1;
    ax += __shfl_down(ax, 32, 64);
    ay += __shfl_down(ay, 32, 64);
    if (lane < 32) {
        float2* a2 = (float2*)(accb + (size_t)b * 64 + 2 * d);
        float2 o = *a2;
        o.x += ax; o.y += ay;
        *a2 = o;
    }
}

// ---------------------------------------------------------------------------
// Batch accumulator init (fp32 weights -> fp32 ACCB; layer-0 term exact).
// ---------------------------------------------------------------------------
__global__ void batch_init(const float4* __restrict__ uw,
                           const float4* __restrict__ iw,
                           const int* __restrict__ users,
                           const int* __restrict__ items,
                           float4* __restrict__ accb) {
    int tid = blockIdx.x * blockDim.x + threadIdx.x;   // row*16 + q
    const int total = 2 * BATCH * (DIM / 4);
    if (tid >= total) return;
    int r = tid >> 4;
    int q = tid & 15;
    float4 v;
    if (r < BATCH) v = uw[(size_t)users[r] * 16 + q];
    else           v = iw[(size_t)items[r - BATCH] * 16 + q];
    accb[tid] = v;
}

// ---------------------------------------------------------------------------
// Batch accumulator add from fp16 node table (layers 1,2).
// ---------------------------------------------------------------------------
__global__ void batch_add(const __half* __restrict__ emb,
                          const int* __restrict__ users,
                          const int* __restrict__ items,
                          float4* __restrict__ accb) {
    int tid = blockIdx.x * blockDim.x + threadIdx.x;
    const int total = 2 * BATCH * (DIM / 4);
    if (tid >= total) return;
    int r = tid >> 4;
    int q = tid & 15;
    int node = (r < BATCH) ? users[r] : (N_USERS + items[r - BATCH]);
    const __half2* e2 = (const __half2*)(emb + (size_t)node * 64 + q * 4);
    float2 lo = __half22float2(e2[0]);
    float2 hi = __half22float2(e2[1]);
    float4 a = accb[tid];
    a.x += lo.x; a.y += lo.y; a.z += hi.x; a.w += hi.y;
    accb[tid] = a;
}

// ---------------------------------------------------------------------------
// Final dot: out[b] = (accb[b] . accb[BATCH+b]) / 16
// ---------------------------------------------------------------------------
__global__ void final_dot(const float* __restrict__ accb,
                          float* __restrict__ out) {
    int b = blockIdx.x * 4 + (threadIdx.x >> 6);
    int lane = threadIdx.x & 63;
    if (b >= BATCH) return;
    float pu = accb[(size_t)b * 64 + lane];
    float pi = accb[(size_t)(BATCH + b) * 64 + lane];
    float p = pu * pi;
    #pragma unroll
    for (int off = 32; off > 0; off >>= 1)
        p += __shfl_down(p, off, 64);
    if (lane == 0) out[b] = p * (1.0f / 16.0f);
}

extern "C" void kernel_launch(void* const* d_in, const int* in_sizes, int n_in,
                              void* d_out, int out_size, void* d_ws, size_t ws_size,
                              hipStream_t stream) {
    const float* uw   = (const float*)d_in[0];
    const float* iw   = (const float*)d_in[1];
    const float* tw   = (const float*)d_in[2];
    const float* vals = (const float*)d_in[3];
    const int*   row  = (const int*)d_in[4];
    const int*   col  = (const int*)d_in[5];
    const int*   users= (const int*)d_in[6];
    const int*   items= (const int*)d_in[7];
    float* out = (float*)d_out;

    // ---- workspace layout (no aliasing; ~114 MB total) ----
    char* ws = (char*)d_ws;
    const size_t NODE_F = (size_t)N_NODES * DIM;       // 9,664,000 elements
    __half* A     = (__half*)ws; ws += NODE_F * 2;     // 19.33 MB
    __half* B     = (__half*)ws; ws += NODE_F * 2;     // 19.33 MB
    float* ACCB   = (float*)ws;  ws += (size_t)2 * BATCH * DIM * 4;
    int*   bcnt   = (int*)ws;    ws += (size_t)NB * 4;
    int*   bptr   = (int*)ws;    ws += (size_t)(NB + 1) * 4;
    int*   rowptr = (int*)ws;    ws += (size_t)(N_NODES + 1) * 4;
    int*   hcnt   = (int*)ws;    ws += (size_t)NPART * NB * 4;   // 2.42 MB
    int2*  cv     = (int2*)ws;   ws += (size_t)NNZ * 8;          // 32 MB
    int2*  cvtmp  = (int2*)ws;   ws += (size_t)NNZ * 8;          // 32 MB

    const int node_v4  = N_NODES * (DIM / 4);
    const int batch_v4 = 2 * BATCH * (DIM / 4);

    // ---- layer-0 embedding (fp16) + batch accumulator init (fp32) ----
    concat_init<<<(node_v4 + 255) / 256, 256, 0, stream>>>(
        (const float4*)uw, (const float4*)iw, (const float4*)tw, (__half2*)A);
    batch_init<<<(batch_v4 + 255) / 256, 256, 0, stream>>>(
        (const float4*)uw, (const float4*)iw, users, items, (float4*)ACCB);

    // ---- atomic-free bucketed partition + bucket-local sort -> CSR ----
    part_count<<<NPART, 256, 0, stream>>>(row, hcnt);
    part_scanA<<<(NB + 3) / 4, 256, 0, stream>>>(hcnt, bcnt);
    part_scanB<<<1, 1024, 0, stream>>>(bcnt, bptr, rowptr);
    part_scatter<<<NPART, 256, 0, stream>>>(row, col, vals, hcnt, bptr, cvtmp);
    bucket_sort<<<NB, 256, 0, stream>>>(bptr, (const long long*)cvtmp, cv, rowptr);

    // ---- layers 1,2: full SpMM (fp16 tables); layer 3: batch rows only ----
    const int spmm_blocks = ((NB + 7) / 8) * 256;   // 148*256 = 37888
    spmm_csr<<<spmm_blocks, 256, 0, stream>>>(rowptr, cv, (const __half2*)A,
                                              (__half2*)B);
    batch_add<<<(batch_v4 + 255) / 256, 256, 0, stream>>>(
        B, users, items, (float4*)ACCB);
    spmm_csr<<<spmm_blocks, 256, 0, stream>>>(rowptr, cv, (const __half2*)B,
                                              (__half2*)A);
    batch_add<<<(batch_v4 + 255) / 256, 256, 0, stream>>>(
        A, users, items, (float4*)ACCB);
    spmm_batch<<<(2 * BATCH + 3) / 4, 256, 0, stream>>>(
        rowptr, cv, (const __half2*)A, users, items, ACCB);

    final_dot<<<(BATCH + 3) / 4, 256, 0, stream>>>(ACCB, out);
}

// Round 13
// 493.266 us; speedup vs baseline: 1.5079x; 1.0726x over previous
//
#include <hip/hip_runtime.h>
#include <hip/hip_fp16.h>

#define N_USERS 100000
#define N_ITEMS 50000
#define N_TOPICS 1000
#define N_NODES (N_USERS + N_ITEMS + N_TOPICS)   // 151000
#define DIM 64
#define NNZ 4000000
#define BATCH 16384

#define BROWS 128                                 // rows per bucket
#define NB ((N_NODES + BROWS - 1) / BROWS)        // 1180 buckets
#define NPART 512                                 // partition blocks
#define CHUNK ((NNZ + NPART - 1) / NPART)         // 7813 edges per block
#define SEGCAP 4608                               // LDS seg capacity (36 KB)

// ---------------------------------------------------------------------------
// Build X0 = concat(user_w, item_w, topic_w) in FP16. One float4 (4 dims)
// per thread, stored as two __half2.
// ---------------------------------------------------------------------------
__global__ void concat_init(const float4* __restrict__ uw,
                            const float4* __restrict__ iw,
                            const float4* __restrict__ tw,
                            __half2* __restrict__ x0) {
    int tid = blockIdx.x * blockDim.x + threadIdx.x;   // node*16 + q
    const int total = N_NODES * (DIM / 4);
    if (tid >= total) return;
    int node = tid >> 4;
    int q = tid & 15;
    float4 v;
    if (node < N_USERS)                v = uw[node * 16 + q];
    else if (node < N_USERS + N_ITEMS) v = iw[(node - N_USERS) * 16 + q];
    else                               v = tw[(node - N_USERS - N_ITEMS) * 16 + q];
    x0[tid * 2]     = __floats2half2_rn(v.x, v.y);
    x0[tid * 2 + 1] = __floats2half2_rn(v.z, v.w);
}

// ---------------------------------------------------------------------------
// Partition phase 1: per-block bucket histogram of its contiguous chunk.
// 1024 threads: 512 blocks x 16 waves = 32 waves/CU (full occupancy).
// ---------------------------------------------------------------------------
__global__ void __launch_bounds__(1024)
part_count(const int* __restrict__ row, int* __restrict__ hcnt) {
    __shared__ int h[NB];
    const int g = blockIdx.x;
    const int t = threadIdx.x;
    for (int i = t; i < NB; i += 1024) h[i] = 0;
    __syncthreads();
    int e0 = g * CHUNK;
    int e1 = e0 + CHUNK; if (e1 > NNZ) e1 = NNZ;
    for (int e = e0 + t; e < e1; e += 1024) {
        int r = __builtin_nontemporal_load(&row[e]);
        atomicAdd(&h[r >> 7], 1);
    }
    __syncthreads();
    int* dst = hcnt + (size_t)g * NB;
    for (int i = t; i < NB; i += 1024) dst[i] = h[i];
}

// ---------------------------------------------------------------------------
// Partition phase 2a: per-bucket exclusive scan across the NPART blocks.
// ---------------------------------------------------------------------------
__global__ void part_scanA(int* __restrict__ hcnt, int* __restrict__ bcnt) {
    int b = blockIdx.x * 4 + (threadIdx.x >> 6);
    int lane = threadIdx.x & 63;
    if (b >= NB) return;
    int carry = 0;
    for (int base = 0; base < NPART; base += 64) {
        int g = base + lane;
        int v = hcnt[(size_t)g * NB + b];
        int x = v;
        #pragma unroll
        for (int off = 1; off < 64; off <<= 1) {
            int y = __shfl_up(x, off, 64);
            if (lane >= off) x += y;
        }
        int tot = __shfl(x, 63, 64);
        hcnt[(size_t)g * NB + b] = carry + x - v;
        carry += tot;
    }
    if (lane == 0) bcnt[b] = carry;
}

// ---------------------------------------------------------------------------
// Partition phase 2b: exclusive scan over NB bucket totals (single block).
// ---------------------------------------------------------------------------
__global__ void part_scanB(const int* __restrict__ bcnt,
                           int* __restrict__ bptr,
                           int* __restrict__ rowptr) {
    __shared__ int wsum[16];
    __shared__ int carry_s;
    const int t = threadIdx.x;
    const int lane = t & 63;
    const int wid = t >> 6;
    if (t == 0) carry_s = 0;
    __syncthreads();
    for (int base = 0; base < NB; base += 1024) {
        int i = base + t;
        int v = (i < NB) ? bcnt[i] : 0;
        int x = v;
        #pragma unroll
        for (int off = 1; off < 64; off <<= 1) {
            int y = __shfl_up(x, off, 64);
            if (lane >= off) x += y;
        }
        if (lane == 63) wsum[wid] = x;
        __syncthreads();
        int wbase = 0;
        for (int w = 0; w < wid; ++w) wbase += wsum[w];
        int excl = carry_s + wbase + (x - v);
        if (i < NB) bptr[i] = excl;
        __syncthreads();
        if (t == 1023) carry_s = excl + v;
        __syncthreads();
    }
    if (t == 0) { bptr[NB] = NNZ; rowptr[N_NODES] = NNZ; }
}

// ---------------------------------------------------------------------------
// Partition phase 3: atomic-free scatter via per-(block,bucket) offsets.
// 1024 threads for full occupancy; same CHUNK (preserves ~6.6-record
// contiguous per-(block,bucket) runs that merge in L2).
// ---------------------------------------------------------------------------
__global__ void __launch_bounds__(1024)
part_scatter(const int* __restrict__ row,
             const int* __restrict__ col,
             const float* __restrict__ vals,
             const int* __restrict__ hcnt,
             const int* __restrict__ bptr,
             int2* __restrict__ cvtmp) {
    __shared__ int cur[NB];
    const int g = blockIdx.x;
    const int t = threadIdx.x;
    const int* hoff = hcnt + (size_t)g * NB;
    for (int i = t; i < NB; i += 1024) cur[i] = bptr[i] + hoff[i];
    __syncthreads();
    int e0 = g * CHUNK;
    int e1 = e0 + CHUNK; if (e1 > NNZ) e1 = NNZ;
    for (int e = e0 + t; e < e1; e += 1024) {
        int r = __builtin_nontemporal_load(&row[e]);
        int c = __builtin_nontemporal_load(&col[e]);
        float v = __builtin_nontemporal_load(&vals[e]);
        int p = atomicAdd(&cur[r >> 7], 1);
        cvtmp[p] = make_int2(((r & (BROWS - 1)) << 18) | c, __float_as_int(v));
    }
}

// ---------------------------------------------------------------------------
// Bucket-local counting sort -> row-sorted CSR (cv) + rowptr.
// Segment staged in LDS once (<=36 KB); normal stores for cv.
// ---------------------------------------------------------------------------
__global__ void __launch_bounds__(256)
bucket_sort(const int* __restrict__ bptr,
            const long long* __restrict__ cvtmp,
            int2* __restrict__ cv,
            int* __restrict__ rowptr) {
    __shared__ int2 seg[SEGCAP];     // 36 KB
    __shared__ int cnt[BROWS];
    __shared__ int cur[BROWS];
    const int t = threadIdx.x;
    const int b = blockIdx.x;
    const int beg = bptr[b];
    const int end = bptr[b + 1];
    const int n = end - beg;

    for (int i = t; i < BROWS; i += 256) cnt[i] = 0;
    const bool lds_path = (n <= SEGCAP);

    if (lds_path) {
        for (int j = t; j < n; j += 256) {
            long long e = cvtmp[beg + j];
            seg[j] = make_int2((int)e, (int)(e >> 32));
        }
    }
    __syncthreads();

    // pass 1: per-row counts
    if (lds_path) {
        for (int j = t; j < n; j += 256)
            atomicAdd(&cnt[(seg[j].x >> 18) & (BROWS - 1)], 1);
    } else {
        for (int j = beg + t; j < end; j += 256) {
            long long e = cvtmp[j];
            atomicAdd(&cnt[((int)e >> 18) & (BROWS - 1)], 1);
        }
    }
    __syncthreads();

    // exclusive scan of 128 counts on wave 0; also emit rowptr
    if (t < 64) {
        int lane = t;
        int v0 = cnt[lane];
        int v1 = cnt[64 + lane];
        int x0 = v0;
        #pragma unroll
        for (int off = 1; off < 64; off <<= 1) {
            int y = __shfl_up(x0, off, 64);
            if (lane >= off) x0 += y;
        }
        int tot0 = __shfl(x0, 63, 64);
        int x1 = v1;
        #pragma unroll
        for (int off = 1; off < 64; off <<= 1) {
            int y = __shfl_up(x1, off, 64);
            if (lane >= off) x1 += y;
        }
        x1 += tot0;
        int e0 = x0 - v0;
        int e1 = x1 - v1;
        cur[lane] = e0;
        cur[64 + lane] = e1;
        int rowbase = b * BROWS;
        if (rowbase + lane < N_NODES)      rowptr[rowbase + lane] = beg + e0;
        if (rowbase + 64 + lane < N_NODES) rowptr[rowbase + 64 + lane] = beg + e1;
    }
    __syncthreads();

    // pass 2: scatter into row-sorted order, strip row bits
    if (lds_path) {
        for (int j = t; j < n; j += 256) {
            int2 e = seg[j];
            int p = atomicAdd(&cur[(e.x >> 18) & (BROWS - 1)], 1);
            cv[beg + p] = make_int2(e.x & 0x3FFFF, e.y);
        }
    } else {
        for (int j = beg + t; j < end; j += 256) {
            long long e = cvtmp[j];
            int lo = (int)e;
            int hi = (int)(e >> 32);
            int p = atomicAdd(&cur[(lo >> 18) & (BROWS - 1)], 1);
            cv[beg + p] = make_int2(lo & 0x3FFFF, hi);
        }
    }
}

// ---------------------------------------------------------------------------
// SpMM over CSR, FP16 tables, half-wave-per-edge, unroll-8 per half
// (16 gathers in flight per wave). fp32 accumulation; cross-half shfl
// combine; lanes<32 store the row.
// ---------------------------------------------------------------------------
__global__ void spmm_csr(const int* __restrict__ rowptr,
                         const int2* __restrict__ cv,
                         const __half2* __restrict__ x2,
                         __half2* __restrict__ y2) {
    int blk = blockIdx.x;
    int bucket = (blk >> 8) * 8 + (blk & 7);
    int sub = (blk & 255) >> 3;
    int r = bucket * BROWS + sub * 4 + (threadIdx.x >> 6);
    if (r >= N_NODES) return;
    int lane = threadIdx.x & 63;
    int half = lane >> 5;
    int d = lane & 31;
    int beg = rowptr[r];
    int end = rowptr[r + 1];
    float ax0 = 0.0f, ay0 = 0.0f, ax1 = 0.0f, ay1 = 0.0f;
    int j = beg + half;                 // this half's edge stream, stride 2
    for (; j + 14 < end; j += 16) {     // 8 edges per half per iter
        int2 e[8];
        __half2 h[8];
        #pragma unroll
        for (int k = 0; k < 8; ++k) e[k] = cv[j + 2 * k];
        #pragma unroll
        for (int k = 0; k < 8; ++k) h[k] = x2[(size_t)e[k].x * 32 + d];
        #pragma unroll
        for (int k = 0; k < 8; k += 2) {
            float2 f0 = __half22float2(h[k]);
            float2 f1 = __half22float2(h[k + 1]);
            float v0 = __int_as_float(e[k].y);
            float v1 = __int_as_float(e[k + 1].y);
            ax0 = fmaf(v0, f0.x, ax0); ay0 = fmaf(v0, f0.y, ay0);
            ax1 = fmaf(v1, f1.x, ax1); ay1 = fmaf(v1, f1.y, ay1);
        }
    }
    for (; j + 6 < end; j += 8) {       // 4 edges per half
        int2 e0 = cv[j];
        int2 e1 = cv[j + 2];
        int2 e2 = cv[j + 4];
        int2 e3 = cv[j + 6];
        float2 f0 = __half22float2(x2[(size_t)e0.x * 32 + d]);
        float2 f1 = __half22float2(x2[(size_t)e1.x * 32 + d]);
        float2 f2 = __half22float2(x2[(size_t)e2.x * 32 + d]);
        float2 f3 = __half22float2(x2[(size_t)e3.x * 32 + d]);
        float v0 = __int_as_float(e0.y);
        float v1 = __int_as_float(e1.y);
        float v2 = __int_as_float(e2.y);
        float v3 = __int_as_float(e3.y);
        ax0 = fmaf(v0, f0.x, ax0); ay0 = fmaf(v0, f0.y, ay0);
        ax1 = fmaf(v1, f1.x, ax1); ay1 = fmaf(v1, f1.y, ay1);
        ax0 = fmaf(v2, f2.x, ax0); ay0 = fmaf(v2, f2.y, ay0);
        ax1 = fmaf(v3, f3.x, ax1); ay1 = fmaf(v3, f3.y, ay1);
    }
    for (; j < end; j += 2) {
        int2 e = cv[j];
        float2 f = __half22float2(x2[(size_t)e.x * 32 + d]);
        float v = __int_as_float(e.y);
        ax0 = fmaf(v, f.x, ax0); ay0 = fmaf(v, f.y, ay0);
    }
    float ax = ax0 + ax1;
    float ay = ay0 + ay1;
    ax += __shfl_down(ax, 32, 64);
    ay += __shfl_down(ay, 32, 64);
    if (lane < 32) y2[(size_t)r * 32 + d] = __floats2half2_rn(ax, ay);
}

// ---------------------------------------------------------------------------
// Layer-3 SpMM restricted to batch rows (~870K edges), same structure,
// fp32 accumulation straight into ACCB (float2 RMW).
// ---------------------------------------------------------------------------
__global__ void spmm_batch(const int* __restrict__ rowptr,
                           const int2* __restrict__ cv,
                           const __half2* __restrict__ x2,
                           const int* __restrict__ users,
                           const int* __restrict__ items,
                           float* __restrict__ accb) {
    int b = blockIdx.x * 4 + (threadIdx.x >> 6);
    if (b >= 2 * BATCH) return;
    int lane = threadIdx.x & 63;
    int half = lane >> 5;
    int d = lane & 31;
    int r = (b < BATCH) ? users[b] : (N_USERS + items[b - BATCH]);
    int beg = rowptr[r];
    int end = rowptr[r + 1];
    float ax0 = 0.0f, ay0 = 0.0f, ax1 = 0.0f, ay1 = 0.0f;
    int j = beg + half;
    for (; j + 14 < end; j += 16) {
        int2 e[8];
        __half2 h[8];
        #pragma unroll
        for (int k = 0; k < 8; ++k) e[k] = cv[j + 2 * k];
        #pragma unroll
        for (int k = 0; k < 8; ++k) h[k] = x2[(size_t)e[k].x * 32 + d];
        #pragma unroll
        for (int k = 0; k < 8; k += 2) {
            float2 f0 = __half22float2(h[k]);
            float2 f1 = __half22float2(h[k + 1]);
            float v0 = __int_as_float(e[k].y);
            float v1 = __int_as_float(e[k + 1].y);
            ax0 = fmaf(v0, f0.x, ax0); ay0 = fmaf(v0, f0.y, ay0);
            ax1 = fmaf(v1, f1.x, ax1); ay1 = fmaf(v1, f1.y, ay1);
        }
    }
    for (; j + 6 < end; j += 8) {
        int2 e0 = cv[j];
        int2 e1 = cv[j + 2];
        int2 e2 = cv[j + 4];
        int2 e3 = cv[j + 6];
        float2 f0 = __half22float2(x2[(size_t)e0.x * 32 + d]);
        float2 f1 = __half22float2(x2[(size_t)e1.x * 32 + d]);
        float2 f2 = __half22float2(x2[(size_t)e2.x * 32 + d]);
        float2 f3 = __half22float2(x2[(size_t)e3.x * 32 + d]);
        float v0 = __int_as_float(e0.y);
        float v1 = __int_as_float(e1.y);
        float v2 = __int_as_float(e2.y);
        float v3 = __int_as_float(e3.y);
        ax0 = fmaf(v0, f0.x, ax0); ay0 = fmaf(v0, f0.y, ay0);
        ax1 = fmaf(v1, f1.x, ax1); ay1 = fmaf(v1, f1.y, ay1);
        ax0 = fmaf(v2, f2.x, ax0); ay0 = fmaf(v2, f2.y, ay0);
        ax1 = fmaf(v3, f3.x, ax1); ay1 = fmaf(v3, f3.y, ay1);
    }
    for (; j < end; j += 2) {
        int2 e = cv[j];
        float2 f = __half22float2(x2[(size_t)e.x * 32 + d]);
        float v = __int_as_float(e.y);
        ax0 = fmaf(v, f.x, ax0); ay0 = fmaf(v, f.y, ay0);
    }
    float ax = ax0 + ax1;
    float ay = ay0 + ay1;
    ax += __shfl_down(ax, 32, 64);
    ay += __shfl_down(ay, 32, 64);
    if (lane < 32) {
        float2* a2 = (float2*)(accb + (size_t)b * 64 + 2 * d);
        float2 o = *a2;
        o.x += ax; o.y += ay;
        *a2 = o;
    }
}

// ---------------------------------------------------------------------------
// Batch accumulator init (fp32 weights -> fp32 ACCB; layer-0 term exact).
// ---------------------------------------------------------------------------
__global__ void batch_init(const float4* __restrict__ uw,
                           const float4* __restrict__ iw,
                           const int* __restrict__ users,
                           const int* __restrict__ items,
                           float4* __restrict__ accb) {
    int tid = blockIdx.x * blockDim.x + threadIdx.x;   // row*16 + q
    const int total = 2 * BATCH * (DIM / 4);
    if (tid >= total) return;
    int r = tid >> 4;
    int q = tid & 15;
    float4 v;
    if (r < BATCH) v = uw[(size_t)users[r] * 16 + q];
    else           v = iw[(size_t)items[r - BATCH] * 16 + q];
    accb[tid] = v;
}

// ---------------------------------------------------------------------------
// Batch accumulator add from fp16 node table (layers 1,2).
// ---------------------------------------------------------------------------
__global__ void batch_add(const __half* __restrict__ emb,
                          const int* __restrict__ users,
                          const int* __restrict__ items,
                          float4* __restrict__ accb) {
    int tid = blockIdx.x * blockDim.x + threadIdx.x;
    const int total = 2 * BATCH * (DIM / 4);
    if (tid >= total) return;
    int r = tid >> 4;
    int q = tid & 15;
    int node = (r < BATCH) ? users[r] : (N_USERS + items[r - BATCH]);
    const __half2* e2 = (const __half2*)(emb + (size_t)node * 64 + q * 4);
    float2 lo = __half22float2(e2[0]);
    float2 hi = __half22float2(e2[1]);
    float4 a = accb[tid];
    a.x += lo.x; a.y += lo.y; a.z += hi.x; a.w += hi.y;
    accb[tid] = a;
}

// ---------------------------------------------------------------------------
// Final dot: out[b] = (accb[b] . accb[BATCH+b]) / 16
// ---------------------------------------------------------------------------
__global__ void final_dot(const float* __restrict__ accb,
                          float* __restrict__ out) {
    int b = blockIdx.x * 4 + (threadIdx.x >> 6);
    int lane = threadIdx.x & 63;
    if (b >= BATCH) return;
    float pu = accb[(size_t)b * 64 + lane];
    float pi = accb[(size_t)(BATCH + b) * 64 + lane];
    float p = pu * pi;
    #pragma unroll
    for (int off = 32; off > 0; off >>= 1)
        p += __shfl_down(p, off, 64);
    if (lane == 0) out[b] = p * (1.0f / 16.0f);
}

extern "C" void kernel_launch(void* const* d_in, const int* in_sizes, int n_in,
                              void* d_out, int out_size, void* d_ws, size_t ws_size,
                              hipStream_t stream) {
    const float* uw   = (const float*)d_in[0];
    const float* iw   = (const float*)d_in[1];
    const float* tw   = (const float*)d_in[2];
    const float* vals = (const float*)d_in[3];
    const int*   row  = (const int*)d_in[4];
    const int*   col  = (const int*)d_in[5];
    const int*   users= (const int*)d_in[6];
    const int*   items= (const int*)d_in[7];
    float* out = (float*)d_out;

    // ---- workspace layout (no aliasing; ~114 MB total) ----
    char* ws = (char*)d_ws;
    const size_t NODE_F = (size_t)N_NODES * DIM;       // 9,664,000 elements
    __half* A     = (__half*)ws; ws += NODE_F * 2;     // 19.33 MB
    __half* B     = (__half*)ws; ws += NODE_F * 2;     // 19.33 MB
    float* ACCB   = (float*)ws;  ws += (size_t)2 * BATCH * DIM * 4;
    int*   bcnt   = (int*)ws;    ws += (size_t)NB * 4;
    int*   bptr   = (int*)ws;    ws += (size_t)(NB + 1) * 4;
    int*   rowptr = (int*)ws;    ws += (size_t)(N_NODES + 1) * 4;
    int*   hcnt   = (int*)ws;    ws += (size_t)NPART * NB * 4;   // 2.42 MB
    int2*  cv     = (int2*)ws;   ws += (size_t)NNZ * 8;          // 32 MB
    int2*  cvtmp  = (int2*)ws;   ws += (size_t)NNZ * 8;          // 32 MB

    const int node_v4  = N_NODES * (DIM / 4);
    const int batch_v4 = 2 * BATCH * (DIM / 4);

    // ---- layer-0 embedding (fp16) + batch accumulator init (fp32) ----
    concat_init<<<(node_v4 + 255) / 256, 256, 0, stream>>>(
        (const float4*)uw, (const float4*)iw, (const float4*)tw, (__half2*)A);
    batch_init<<<(batch_v4 + 255) / 256, 256, 0, stream>>>(
        (const float4*)uw, (const float4*)iw, users, items, (float4*)ACCB);

    // ---- atomic-free bucketed partition + bucket-local sort -> CSR ----
    part_count<<<NPART, 1024, 0, stream>>>(row, hcnt);
    part_scanA<<<(NB + 3) / 4, 256, 0, stream>>>(hcnt, bcnt);
    part_scanB<<<1, 1024, 0, stream>>>(bcnt, bptr, rowptr);
    part_scatter<<<NPART, 1024, 0, stream>>>(row, col, vals, hcnt, bptr, cvtmp);
    bucket_sort<<<NB, 256, 0, stream>>>(bptr, (const long long*)cvtmp, cv, rowptr);

    // ---- layers 1,2: full SpMM (fp16 tables); layer 3: batch rows only ----
    const int spmm_blocks = ((NB + 7) / 8) * 256;   // 148*256 = 37888
    spmm_csr<<<spmm_blocks, 256, 0, stream>>>(rowptr, cv, (const __half2*)A,
                                              (__half2*)B);
    batch_add<<<(batch_v4 + 255) / 256, 256, 0, stream>>>(
        B, users, items, (float4*)ACCB);
    spmm_csr<<<spmm_blocks, 256, 0, stream>>>(rowptr, cv, (const __half2*)B,
                                              (__half2*)A);
    batch_add<<<(batch_v4 + 255) / 256, 256, 0, stream>>>(
        A, users, items, (float4*)ACCB);
    spmm_batch<<<(2 * BATCH + 3) / 4, 256, 0, stream>>>(
        rowptr, cv, (const __half2*)A, users, items, ACCB);

    final_dot<<<(BATCH + 3) / 4, 256, 0, stream>>>(ACCB, out);
}